// Round 1
// baseline (1483.291 us; speedup 1.0000x reference)
//
#include <hip/hip_runtime.h>
#include <hip/hip_bf16.h>

#define D 128
#define NGRAPHS 64
#define NCLASSES 16

__device__ __forceinline__ float sigf(float x) {
    return 1.0f / (1.0f + __expf(-x));
}

// ---------------- GEMM: C[N,128] = A0@W0 (+ A1@W1) + epilogue ----------------
// K = 128 fixed. BM=64 rows/block, BN=128 (full width). 256 threads, 4x8 per thread.
// EPI: 0 none, 1 sigmoid(acc+bias), 2 sigmoid(acc+bias)*aux0, 3 acc+bias,
//      4 relu(acc+bias), 5 GRU: z*((acc+bias)*g)+(1-z)*h  (aux0=g, aux1=z, aux2=h)
template <int EPI>
__launch_bounds__(256)
__global__ void gemm_nk128(const float* __restrict__ A0, const float* __restrict__ W0,
                           const float* __restrict__ A1, const float* __restrict__ W1,
                           float* __restrict__ C, int N,
                           const float* __restrict__ bias,
                           const float* __restrict__ aux0,
                           const float* __restrict__ aux1,
                           const float* __restrict__ aux2) {
    __shared__ float As[32][64];
    __shared__ float Ws[32][128];
    const int tid = threadIdx.x;
    const int tx = tid & 15;   // col group (8 cols each)
    const int ty = tid >> 4;   // row group (4 rows each)
    const int r0 = blockIdx.x * 64;

    float acc[4][8];
#pragma unroll
    for (int i = 0; i < 4; i++)
#pragma unroll
        for (int j = 0; j < 8; j++) acc[i][j] = 0.f;

    const int npass = (A1 != nullptr) ? 2 : 1;
    for (int pass = 0; pass < npass; ++pass) {
        const float* __restrict__ A = pass ? A1 : A0;
        const float* __restrict__ W = pass ? W1 : W0;
        for (int kc = 0; kc < 128; kc += 32) {
            __syncthreads();
            // A tile: 64 rows x 32 k, stored transposed As[k][r]
#pragma unroll
            for (int i = 0; i < 2; i++) {
                int q = tid + i * 256;        // 0..511
                int r = q >> 3;
                int kq = q & 7;
                float4 v = make_float4(0.f, 0.f, 0.f, 0.f);
                int row = r0 + r;
                if (row < N) v = *(const float4*)(A + (size_t)row * D + kc + kq * 4);
                As[kq * 4 + 0][r] = v.x;
                As[kq * 4 + 1][r] = v.y;
                As[kq * 4 + 2][r] = v.z;
                As[kq * 4 + 3][r] = v.w;
            }
            // W tile: 32 k x 128 c
#pragma unroll
            for (int i = 0; i < 4; i++) {
                int q = tid + i * 256;        // 0..1023
                int k = q >> 5;
                int cq = q & 31;
                float4 v = *(const float4*)(W + (size_t)(kc + k) * D + cq * 4);
                *(float4*)&Ws[k][cq * 4] = v;
            }
            __syncthreads();
#pragma unroll
            for (int k = 0; k < 32; k++) {
                float4 a = *(const float4*)&As[k][ty * 4];
                float4 b0 = *(const float4*)&Ws[k][tx * 8];
                float4 b1 = *(const float4*)&Ws[k][tx * 8 + 4];
                float av[4] = {a.x, a.y, a.z, a.w};
                float bv[8] = {b0.x, b0.y, b0.z, b0.w, b1.x, b1.y, b1.z, b1.w};
#pragma unroll
                for (int i = 0; i < 4; i++)
#pragma unroll
                    for (int j = 0; j < 8; j++) acc[i][j] += av[i] * bv[j];
            }
        }
    }

#pragma unroll
    for (int i = 0; i < 4; i++) {
        int row = r0 + ty * 4 + i;
        if (row >= N) break;
        size_t base = (size_t)row * D + tx * 8;
        float vals[8];
#pragma unroll
        for (int j = 0; j < 8; j++) {
            int c = tx * 8 + j;
            float v = acc[i][j];
            if (EPI == 1) v = sigf(v + bias[c]);
            else if (EPI == 2) v = sigf(v + bias[c]) * aux0[base + j];
            else if (EPI == 3) v = v + bias[c];
            else if (EPI == 4) v = fmaxf(v + bias[c], 0.f);
            else if (EPI == 5) {
                float g = aux0[base + j];
                float zz = aux1[base + j];
                float hh = aux2[base + j];
                v = zz * ((v + bias[c]) * g) + (1.f - zz) * hh;
            }
            vals[j] = v;
        }
        *(float4*)(C + base) = make_float4(vals[0], vals[1], vals[2], vals[3]);
        *(float4*)(C + base + 4) = make_float4(vals[4], vals[5], vals[6], vals[7]);
    }
}

// ---------------- CSR build ----------------
__global__ void count_kernel(const int* __restrict__ ei, int* __restrict__ cnt, int E) {
    int e = blockIdx.x * 256 + threadIdx.x;
    if (e < E) atomicAdd(&cnt[ei[E + e]], 1);
}

__global__ void scan_kernel(const int* __restrict__ cnt, int* __restrict__ row_ptr,
                            int* __restrict__ cursor, int N) {
    __shared__ int sd[1024];
    __shared__ int s_run;
    int tid = threadIdx.x;
    if (tid == 0) s_run = 0;
    __syncthreads();
    for (int base = 0; base < N; base += 1024) {
        int i = base + tid;
        int v = (i < N) ? cnt[i] : 0;
        sd[tid] = v;
        __syncthreads();
        for (int off = 1; off < 1024; off <<= 1) {
            int add = (tid >= off) ? sd[tid - off] : 0;
            __syncthreads();
            sd[tid] += add;
            __syncthreads();
        }
        int run = s_run;
        int incl = sd[tid];
        if (i < N) {
            int ex = run + incl - v;
            row_ptr[i] = ex;
            cursor[i] = ex;
        }
        __syncthreads();
        if (tid == 1023) s_run = run + sd[1023];
        __syncthreads();
    }
    if (tid == 0) row_ptr[N] = s_run;
}

__global__ void scatter_kernel(const int* __restrict__ ei, const float* __restrict__ ew,
                               int* __restrict__ cursor, int* __restrict__ src_s,
                               float* __restrict__ ew_s, int E) {
    int e = blockIdx.x * 256 + threadIdx.x;
    if (e < E) {
        int d = ei[E + e];
        int pos = atomicAdd(&cursor[d], 1);
        src_s[pos] = ei[e];
        ew_s[pos] = ew[e];
    }
}

// ---------------- aggregation: m[n] = t[n] + sum_{e->n} w_e * t[src_e] ----------------
__global__ void agg_kernel(const float* __restrict__ t, float* __restrict__ m,
                           const int* __restrict__ row_ptr, const int* __restrict__ src_s,
                           const float* __restrict__ ew_s, int N) {
    int n = blockIdx.x * 2 + (threadIdx.x >> 7);
    int c = threadIdx.x & 127;
    if (n >= N) return;
    float acc = t[(size_t)n * D + c];   // self loop, weight 1
    int e0 = row_ptr[n], e1 = row_ptr[n + 1];
    for (int e = e0; e < e1; ++e) {
        acc += ew_s[e] * t[(size_t)src_s[e] * D + c];
    }
    m[(size_t)n * D + c] = acc;
}

// ---------------- bias pack ----------------
__global__ void biaspack_kernel(const float* bzm, const float* bzs, const float* bz0,
                                const float* brm, const float* brs, const float* br0,
                                const float* bhm, const float* bhs, const float* bh0,
                                float* bz, float* br, float* bci) {
    int i = threadIdx.x;
    if (i < D) {
        bz[i] = bzm[i] + bzs[i] + bz0[i];
        br[i] = brm[i] + brs[i] + br0[i];
        bci[i] = bhm[i] + bhs[i] + bh0[i];
    }
}

// ---------------- head: attention gate fused, hA = h * sigmoid(h@Wg + bg) ----------------
__global__ void att_kernel(const float* __restrict__ h, const float* __restrict__ Wg,
                           const float* __restrict__ bg, float* __restrict__ hA, int N) {
    int w = threadIdx.x >> 6, l = threadIdx.x & 63;
    int n = blockIdx.x * 4 + w;
    if (n >= N) return;
    size_t base = (size_t)n * D;
    float h0 = h[base + l], h1 = h[base + 64 + l];
    float p = h0 * Wg[l] + h1 * Wg[64 + l];
#pragma unroll
    for (int off = 32; off; off >>= 1) p += __shfl_xor(p, off);
    float att = sigf(p + bg[0]);
    hA[base + l] = h0 * att;
    hA[base + 64 + l] = h1 * att;
}

__global__ void bounds_kernel(const int* __restrict__ batch, int* __restrict__ gstart,
                              int* __restrict__ gend, int N) {
    int i = blockIdx.x * 256 + threadIdx.x;
    if (i >= N) return;
    int b = batch[i];
    if (i == 0 || batch[i - 1] != b) gstart[b] = i;
    if (i == N - 1 || batch[i + 1] != b) gend[b] = i + 1;
}

__global__ void pool_kernel(const float* __restrict__ ha, const int* __restrict__ gstart,
                            const int* __restrict__ gend, float* __restrict__ pooled) {
    __shared__ float smax[128], ssum[128];
    int g = blockIdx.x;
    int c = threadIdx.x & 127, half = threadIdx.x >> 7;
    int s = gstart[g], e = gend[g];
    float vmax = 0.f, vsum = 0.f;
    for (int n = s + half; n < e; n += 2) {
        float v = ha[(size_t)n * D + c];
        vmax = fmaxf(vmax, v);
        vsum += v;
    }
    if (half == 1) { smax[c] = vmax; ssum[c] = vsum; }
    __syncthreads();
    if (half == 0) {
        vmax = fmaxf(vmax, smax[c]);
        vsum += ssum[c];
        int cnt = e - s;
        pooled[g * 256 + c] = vmax;               // h >= 0 so max(.,0) = .
        pooled[g * 256 + 128 + c] = vsum / (float)max(cnt, 1);
    }
}

__global__ void mlp_kernel(const float* __restrict__ pooled, const float* __restrict__ W1,
                           const float* __restrict__ b1, const float* __restrict__ W2,
                           const float* __restrict__ b2, float* __restrict__ out) {
    __shared__ float hid[128];
    __shared__ float pg[256];
    int g = blockIdx.x, tid = threadIdx.x;
    pg[tid] = pooled[g * 256 + tid];
    __syncthreads();
    if (tid < 128) {
        float acc = b1[tid];
        for (int k = 0; k < 256; k++) acc += pg[k] * W1[k * 128 + tid];
        hid[tid] = fmaxf(acc, 0.f);
    }
    __syncthreads();
    if (tid < 16) {
        float acc = b2[tid];
        for (int k = 0; k < 128; k++) acc += hid[k] * W2[k * 16 + tid];
        out[g * 16 + tid] = acc;
    }
}

// ---------------- host ----------------
static void launch_gemm(int epi, const float* A0, const float* W0, const float* A1,
                        const float* W1, float* C, int N, const float* bias,
                        const float* x0, const float* x1, const float* x2, hipStream_t s) {
    dim3 g((N + 63) / 64), b(256);
    switch (epi) {
        case 0: gemm_nk128<0><<<g, b, 0, s>>>(A0, W0, A1, W1, C, N, bias, x0, x1, x2); break;
        case 1: gemm_nk128<1><<<g, b, 0, s>>>(A0, W0, A1, W1, C, N, bias, x0, x1, x2); break;
        case 2: gemm_nk128<2><<<g, b, 0, s>>>(A0, W0, A1, W1, C, N, bias, x0, x1, x2); break;
        case 3: gemm_nk128<3><<<g, b, 0, s>>>(A0, W0, A1, W1, C, N, bias, x0, x1, x2); break;
        case 4: gemm_nk128<4><<<g, b, 0, s>>>(A0, W0, A1, W1, C, N, bias, x0, x1, x2); break;
        case 5: gemm_nk128<5><<<g, b, 0, s>>>(A0, W0, A1, W1, C, N, bias, x0, x1, x2); break;
    }
}

extern "C" void kernel_launch(void* const* d_in, const int* in_sizes, int n_in,
                              void* d_out, int out_size, void* d_ws, size_t ws_size,
                              hipStream_t stream) {
    const float* x       = (const float*)d_in[0];
    const int*   ei      = (const int*)d_in[1];
    const int*   batch   = (const int*)d_in[2];
    const float* ew      = (const float*)d_in[3];
    const float* Wa      = (const float*)d_in[4];
    const float* Wzm     = (const float*)d_in[5];
    const float* bzm     = (const float*)d_in[6];
    const float* Wzs     = (const float*)d_in[7];
    const float* bzs     = (const float*)d_in[8];
    const float* Wrm     = (const float*)d_in[9];
    const float* brm     = (const float*)d_in[10];
    const float* Wrs     = (const float*)d_in[11];
    const float* brs     = (const float*)d_in[12];
    const float* Whm     = (const float*)d_in[13];
    const float* bhm     = (const float*)d_in[14];
    const float* Whs     = (const float*)d_in[15];
    const float* bhs     = (const float*)d_in[16];
    const float* Whg     = (const float*)d_in[17];
    const float* bhg     = (const float*)d_in[18];
    const float* Whl     = (const float*)d_in[19];
    const float* bhl     = (const float*)d_in[20];
    const float* bias_z  = (const float*)d_in[21];
    const float* bias_r  = (const float*)d_in[22];
    const float* bias_h  = (const float*)d_in[23];
    const float* Wag     = (const float*)d_in[24];
    const float* bag     = (const float*)d_in[25];
    const float* Wae     = (const float*)d_in[26];
    const float* bae     = (const float*)d_in[27];
    const float* Wm1     = (const float*)d_in[28];
    const float* bm1     = (const float*)d_in[29];
    const float* Wm2     = (const float*)d_in[30];
    const float* bm2     = (const float*)d_in[31];
    float* out = (float*)d_out;

    const int N = in_sizes[0] / D;
    const int E = in_sizes[1] / 2;
    const size_t ND = (size_t)N * D;

    // workspace layout
    char* ws = (char*)d_ws;
    float* h_buf = (float*)ws;                ws += ND * 4;
    float* t_buf = (float*)ws;                ws += ND * 4;
    float* m_buf = (float*)ws;                ws += ND * 4;
    float* z_buf = (float*)ws;                ws += ND * 4;
    int*   cnt     = (int*)ws;                ws += (size_t)N * 4;
    int*   row_ptr = (int*)ws;                ws += (size_t)(N + 1) * 4 + 12; // keep align
    int*   cursor  = (int*)ws;                ws += (size_t)N * 4;
    int*   src_s   = (int*)ws;                ws += (size_t)E * 4;
    float* ew_s    = (float*)ws;              ws += (size_t)E * 4;
    float* bz  = (float*)ws;                  ws += D * 4;
    float* br  = (float*)ws;                  ws += D * 4;
    float* bci = (float*)ws;                  ws += D * 4;
    int* gstart = (int*)ws;                   ws += NGRAPHS * 4;
    int* gend   = (int*)ws;                   ws += NGRAPHS * 4;
    float* pooled = (float*)ws;               ws += NGRAPHS * 256 * 4;

    // h = x
    hipMemcpyAsync(h_buf, x, ND * 4, hipMemcpyDeviceToDevice, stream);

    // CSR build (deterministic recompute each call)
    hipMemsetAsync(cnt, 0, (size_t)N * 4, stream);
    count_kernel<<<(E + 255) / 256, 256, 0, stream>>>(ei, cnt, E);
    scan_kernel<<<1, 1024, 0, stream>>>(cnt, row_ptr, cursor, N);
    scatter_kernel<<<(E + 255) / 256, 256, 0, stream>>>(ei, ew, cursor, src_s, ew_s, E);

    biaspack_kernel<<<1, 128, 0, stream>>>(bzm, bzs, bias_z, brm, brs, bias_r,
                                           bhm, bhs, bias_h, bz, br, bci);

    dim3 aggGrid((N + 1) / 2), aggBlk(256);

    for (int layer = 0; layer < 3; ++layer) {
        // t = h @ Wa
        launch_gemm(0, h_buf, Wa, nullptr, nullptr, t_buf, N, nullptr, nullptr, nullptr, nullptr, stream);
        // m = aggregate(t)
        agg_kernel<<<aggGrid, aggBlk, 0, stream>>>(t_buf, m_buf, row_ptr, src_s, ew_s, N);
        // z = sigmoid(m@Wzm + h@Wzs + bz)
        launch_gemm(1, m_buf, Wzm, h_buf, Wzs, z_buf, N, bz, nullptr, nullptr, nullptr, stream);
        // rh = sigmoid(m@Wrm + h@Wrs + br) * h   -> t_buf
        launch_gemm(2, m_buf, Wrm, h_buf, Wrs, t_buf, N, br, h_buf, nullptr, nullptr, stream);
        // ci = m@Whm + rh@Whs + bci  -> m_buf (in place; each block reads its own rows first)
        launch_gemm(3, m_buf, Whm, t_buf, Whs, m_buf, N, bci, nullptr, nullptr, nullptr, stream);
        // g = sigmoid(ci@Whg + bhg)  -> t_buf
        launch_gemm(1, m_buf, Whg, nullptr, nullptr, t_buf, N, bhg, nullptr, nullptr, nullptr, stream);
        // h = z*((ci@Whl + bhl)*g) + (1-z)*h
        launch_gemm(5, m_buf, Whl, nullptr, nullptr, h_buf, N, bhl, t_buf, z_buf, h_buf, stream);
    }

    // head
    att_kernel<<<(N + 3) / 4, 256, 0, stream>>>(h_buf, Wag, bag, t_buf, N);
    launch_gemm(4, t_buf, Wae, nullptr, nullptr, m_buf, N, bae, nullptr, nullptr, nullptr, stream);

    hipMemsetAsync(gstart, 0, NGRAPHS * 4, stream);
    hipMemsetAsync(gend, 0, NGRAPHS * 4, stream);
    bounds_kernel<<<(N + 255) / 256, 256, 0, stream>>>(batch, gstart, gend, N);
    pool_kernel<<<NGRAPHS, 256, 0, stream>>>(m_buf, gstart, gend, pooled);
    mlp_kernel<<<NGRAPHS, 256, 0, stream>>>(pooled, Wm1, bm1, Wm2, bm2, out);
}

// Round 2
// 1032.648 us; speedup vs baseline: 1.4364x; 1.4364x over previous
//
#include <hip/hip_runtime.h>
#include <hip/hip_bf16.h>

#define D 128
#define NGRAPHS 64
#define NCLASSES 16
#define PSPLIT 16

typedef short short8 __attribute__((ext_vector_type(8)));
typedef float f32x4 __attribute__((ext_vector_type(4)));

__device__ __forceinline__ float sigf(float x) {
    return 1.0f / (1.0f + __expf(-x));
}

__device__ __forceinline__ unsigned short f2bf(float x) {
    unsigned u = __float_as_uint(x);
    unsigned r = (u + 0x7fffu + ((u >> 16) & 1u)) >> 16;
    return (unsigned short)r;
}

// ---------------- weight prep: f32 [128][128] -> frag-ordered bf16 hi/lo ----------------
// frag index f = ((j*4 + t)*64 + lane)*8 + s  maps to  W[t*32 + (lane>>4)*8 + s][j*16 + (lane&15)]
__global__ void wprep_kernel(const float* w0, const float* w1, const float* w2,
                             const float* w3, const float* w4, const float* w5,
                             const float* w6, const float* w7, const float* w8,
                             const float* w9, unsigned short* out) {
    const float* ws[10] = {w0, w1, w2, w3, w4, w5, w6, w7, w8, w9};
    const float* W = ws[blockIdx.x];
    unsigned short* oh = out + (size_t)blockIdx.x * 32768;
    unsigned short* ol = oh + 16384;
    for (int f = threadIdx.x; f < 16384; f += 256) {
        int s = f & 7;
        int lane = (f >> 3) & 63;
        int t = (f >> 9) & 3;
        int j = f >> 11;
        int k = t * 32 + ((lane >> 4) << 3) + s;
        int c = (j << 4) + (lane & 15);
        float x = W[k * 128 + c];
        unsigned short hb = f2bf(x);
        float hf = __uint_as_float(((unsigned)hb) << 16);
        unsigned short lb = f2bf(x - hf);
        oh[f] = hb;
        ol[f] = lb;
    }
}

// ---------------- MFMA GEMM: C[N,128] = A0@W0 (+ A1@W1) + epilogue ----------------
// 256 threads = 4 waves, 64 rows/block (16 rows per wave), full 128-col width.
// bf16 hi/lo split: ah*bh + al*bh + ah*bl  (rel err ~2^-16)
// EPI: 0 none, 1 sigmoid(acc+bias), 2 sigmoid(acc+bias)*aux0, 3 acc+bias,
//      4 relu(acc+bias), 5 GRU: z*((acc+bias)*g)+(1-z)*h  (aux0=g, aux1=z, aux2=h)
template <int EPI>
__launch_bounds__(256)
__global__ void gemm_mfma(const float* __restrict__ A0, const unsigned short* __restrict__ W0f,
                          const float* __restrict__ A1, const unsigned short* __restrict__ W1f,
                          float* __restrict__ C, int N,
                          const float* __restrict__ bias,
                          const float* __restrict__ aux0,
                          const float* __restrict__ aux1,
                          const float* __restrict__ aux2) {
    const int tid = threadIdx.x;
    const int wave = tid >> 6;
    const int lane = tid & 63;
    const int r0 = blockIdx.x * 64;

    f32x4 acc[8];
#pragma unroll
    for (int j = 0; j < 8; ++j) acc[j] = (f32x4){0.f, 0.f, 0.f, 0.f};

    int arow = r0 + wave * 16 + (lane & 15);
    if (arow >= N) arow = N - 1;   // clamped rows never stored
    const int kofs = (lane >> 4) << 3;

    const int npass = (A1 != nullptr) ? 2 : 1;
    for (int pass = 0; pass < npass; ++pass) {
        const float* __restrict__ A = pass ? A1 : A0;
        const unsigned short* __restrict__ Wf = pass ? W1f : W0f;
#pragma unroll
        for (int t = 0; t < 4; ++t) {
            const float* ap = A + (size_t)arow * D + t * 32 + kofs;
            float4 a01 = *(const float4*)ap;
            float4 a23 = *(const float4*)(ap + 4);
            float av[8] = {a01.x, a01.y, a01.z, a01.w, a23.x, a23.y, a23.z, a23.w};
            short8 ah, al;
#pragma unroll
            for (int s = 0; s < 8; ++s) {
                float x = av[s];
                unsigned short hb = f2bf(x);
                float hf = __uint_as_float(((unsigned)hb) << 16);
                unsigned short lb = f2bf(x - hf);
                ah[s] = (short)hb;
                al[s] = (short)lb;
            }
#pragma unroll
            for (int j = 0; j < 8; ++j) {
                const unsigned short* bp = Wf + ((((j << 2) + t) << 6) + lane) * 8;
                short8 bh = *(const short8*)bp;
                short8 bl = *(const short8*)(bp + 16384);
                acc[j] = __builtin_amdgcn_mfma_f32_16x16x32_bf16(ah, bh, acc[j], 0, 0, 0);
                acc[j] = __builtin_amdgcn_mfma_f32_16x16x32_bf16(al, bh, acc[j], 0, 0, 0);
                acc[j] = __builtin_amdgcn_mfma_f32_16x16x32_bf16(ah, bl, acc[j], 0, 0, 0);
            }
        }
    }

    // C/D layout (HW-verified): col = lane&15, row = (lane>>4)*4 + reg
    const int col0 = lane & 15;
    const int rbase = r0 + wave * 16 + ((lane >> 4) << 2);
#pragma unroll
    for (int j = 0; j < 8; ++j) {
        int col = (j << 4) + col0;
#pragma unroll
        for (int reg = 0; reg < 4; ++reg) {
            int grow = rbase + reg;
            if (grow >= N) continue;
            size_t o = (size_t)grow * D + col;
            float v = acc[j][reg];
            if (EPI == 1) v = sigf(v + bias[col]);
            else if (EPI == 2) v = sigf(v + bias[col]) * aux0[o];
            else if (EPI == 3) v = v + bias[col];
            else if (EPI == 4) v = fmaxf(v + bias[col], 0.f);
            else if (EPI == 5) {
                float g = aux0[o];
                float zz = aux1[o];
                float hh = aux2[o];
                v = zz * ((v + bias[col]) * g) + (1.f - zz) * hh;
            }
            C[o] = v;
        }
    }
}

// ---------------- CSR build ----------------
__global__ void count_kernel(const int* __restrict__ ei, int* __restrict__ cnt, int E) {
    int e = blockIdx.x * 256 + threadIdx.x;
    if (e < E) atomicAdd(&cnt[ei[E + e]], 1);
}

__global__ void scan_kernel(const int* __restrict__ cnt, int* __restrict__ row_ptr,
                            int* __restrict__ cursor, int N) {
    __shared__ int sd[1024];
    __shared__ int s_run;
    int tid = threadIdx.x;
    if (tid == 0) s_run = 0;
    __syncthreads();
    for (int base = 0; base < N; base += 1024) {
        int i = base + tid;
        int v = (i < N) ? cnt[i] : 0;
        sd[tid] = v;
        __syncthreads();
        for (int off = 1; off < 1024; off <<= 1) {
            int add = (tid >= off) ? sd[tid - off] : 0;
            __syncthreads();
            sd[tid] += add;
            __syncthreads();
        }
        int run = s_run;
        int incl = sd[tid];
        if (i < N) {
            int ex = run + incl - v;
            row_ptr[i] = ex;
            cursor[i] = ex;
        }
        __syncthreads();
        if (tid == 1023) s_run = run + sd[1023];
        __syncthreads();
    }
    if (tid == 0) row_ptr[N] = s_run;
}

__global__ void scatter_kernel(const int* __restrict__ ei, const float* __restrict__ ew,
                               int* __restrict__ cursor, int* __restrict__ src_s,
                               float* __restrict__ ew_s, int E) {
    int e = blockIdx.x * 256 + threadIdx.x;
    if (e < E) {
        int d = ei[E + e];
        int pos = atomicAdd(&cursor[d], 1);
        src_s[pos] = ei[e];
        ew_s[pos] = ew[e];
    }
}

// ---------------- aggregation: m[n] = t[n] + sum_{e->n} w_e * t[src_e] ----------------
__global__ void agg_kernel(const float* __restrict__ t, float* __restrict__ m,
                           const int* __restrict__ row_ptr, const int* __restrict__ src_s,
                           const float* __restrict__ ew_s, int N) {
    int n = blockIdx.x * 2 + (threadIdx.x >> 7);
    int c = threadIdx.x & 127;
    if (n >= N) return;
    float acc = t[(size_t)n * D + c];   // self loop, weight 1
    int e0 = row_ptr[n], e1 = row_ptr[n + 1];
    for (int e = e0; e < e1; ++e) {
        acc += ew_s[e] * t[(size_t)src_s[e] * D + c];
    }
    m[(size_t)n * D + c] = acc;
}

// ---------------- bias pack ----------------
__global__ void biaspack_kernel(const float* bzm, const float* bzs, const float* bz0,
                                const float* brm, const float* brs, const float* br0,
                                const float* bhm, const float* bhs, const float* bh0,
                                float* bz, float* br, float* bci) {
    int i = threadIdx.x;
    if (i < D) {
        bz[i] = bzm[i] + bzs[i] + bz0[i];
        br[i] = brm[i] + brs[i] + br0[i];
        bci[i] = bhm[i] + bhs[i] + bh0[i];
    }
}

// ---------------- head: attention gate fused, hA = h * sigmoid(h@Wg + bg) ----------------
__global__ void att_kernel(const float* __restrict__ h, const float* __restrict__ Wg,
                           const float* __restrict__ bg, float* __restrict__ hA, int N) {
    int w = threadIdx.x >> 6, l = threadIdx.x & 63;
    int n = blockIdx.x * 4 + w;
    if (n >= N) return;
    size_t base = (size_t)n * D;
    float h0 = h[base + l], h1 = h[base + 64 + l];
    float p = h0 * Wg[l] + h1 * Wg[64 + l];
#pragma unroll
    for (int off = 32; off; off >>= 1) p += __shfl_xor(p, off);
    float att = sigf(p + bg[0]);
    hA[base + l] = h0 * att;
    hA[base + 64 + l] = h1 * att;
}

__global__ void bounds_kernel(const int* __restrict__ batch, int* __restrict__ gstart,
                              int* __restrict__ gend, int N) {
    int i = blockIdx.x * 256 + threadIdx.x;
    if (i >= N) return;
    int b = batch[i];
    if (i == 0 || batch[i - 1] != b) gstart[b] = i;
    if (i == N - 1 || batch[i + 1] != b) gend[b] = i + 1;
}

// ---------------- pool: split each graph over PSPLIT blocks, atomic merge ----------------
__global__ void pool2_kernel(const float* __restrict__ ha, const int* __restrict__ gstart,
                             const int* __restrict__ gend, float* __restrict__ pmax,
                             float* __restrict__ psum) {
    int g = blockIdx.x;
    int slice = blockIdx.y;
    int c = threadIdx.x;  // 128 threads
    int s = gstart[g], e = gend[g];
    float vmax = 0.f, vsum = 0.f;
    for (int n = s + slice; n < e; n += PSPLIT) {
        float v = ha[(size_t)n * D + c];
        vmax = fmaxf(vmax, v);
        vsum += v;
    }
    // ha >= 0 (post-ReLU) so float-as-int max is monotone; init is 0
    atomicMax((int*)&pmax[g * D + c], __float_as_int(vmax));
    atomicAdd(&psum[g * D + c], vsum);
}

__global__ void mlp_kernel(const float* __restrict__ pmax, const float* __restrict__ psum,
                           const int* __restrict__ gstart, const int* __restrict__ gend,
                           const float* __restrict__ W1, const float* __restrict__ b1,
                           const float* __restrict__ W2, const float* __restrict__ b2,
                           float* __restrict__ out) {
    __shared__ float hid[128];
    __shared__ float pg[256];
    int g = blockIdx.x, tid = threadIdx.x;
    int cnt = max(gend[g] - gstart[g], 1);
    if (tid < 128) pg[tid] = pmax[g * D + tid];
    else pg[tid] = psum[g * D + (tid - 128)] / (float)cnt;
    __syncthreads();
    if (tid < 128) {
        float acc = b1[tid];
        for (int k = 0; k < 256; k++) acc += pg[k] * W1[k * 128 + tid];
        hid[tid] = fmaxf(acc, 0.f);
    }
    __syncthreads();
    if (tid < 16) {
        float acc = b2[tid];
        for (int k = 0; k < 128; k++) acc += hid[k] * W2[k * 16 + tid];
        out[g * 16 + tid] = acc;
    }
}

// ---------------- host ----------------
static void launch_gemm(int epi, const float* A0, const unsigned short* W0f,
                        const float* A1, const unsigned short* W1f,
                        float* C, int N, const float* bias,
                        const float* x0, const float* x1, const float* x2, hipStream_t s) {
    dim3 g((N + 63) / 64), b(256);
    switch (epi) {
        case 0: gemm_mfma<0><<<g, b, 0, s>>>(A0, W0f, A1, W1f, C, N, bias, x0, x1, x2); break;
        case 1: gemm_mfma<1><<<g, b, 0, s>>>(A0, W0f, A1, W1f, C, N, bias, x0, x1, x2); break;
        case 2: gemm_mfma<2><<<g, b, 0, s>>>(A0, W0f, A1, W1f, C, N, bias, x0, x1, x2); break;
        case 3: gemm_mfma<3><<<g, b, 0, s>>>(A0, W0f, A1, W1f, C, N, bias, x0, x1, x2); break;
        case 4: gemm_mfma<4><<<g, b, 0, s>>>(A0, W0f, A1, W1f, C, N, bias, x0, x1, x2); break;
        case 5: gemm_mfma<5><<<g, b, 0, s>>>(A0, W0f, A1, W1f, C, N, bias, x0, x1, x2); break;
    }
}

extern "C" void kernel_launch(void* const* d_in, const int* in_sizes, int n_in,
                              void* d_out, int out_size, void* d_ws, size_t ws_size,
                              hipStream_t stream) {
    const float* x       = (const float*)d_in[0];
    const int*   ei      = (const int*)d_in[1];
    const int*   batch   = (const int*)d_in[2];
    const float* ew      = (const float*)d_in[3];
    const float* Wa      = (const float*)d_in[4];
    const float* Wzm     = (const float*)d_in[5];
    const float* bzm     = (const float*)d_in[6];
    const float* Wzs     = (const float*)d_in[7];
    const float* bzs     = (const float*)d_in[8];
    const float* Wrm     = (const float*)d_in[9];
    const float* brm     = (const float*)d_in[10];
    const float* Wrs     = (const float*)d_in[11];
    const float* brs     = (const float*)d_in[12];
    const float* Whm     = (const float*)d_in[13];
    const float* bhm     = (const float*)d_in[14];
    const float* Whs     = (const float*)d_in[15];
    const float* bhs     = (const float*)d_in[16];
    const float* Whg     = (const float*)d_in[17];
    const float* bhg     = (const float*)d_in[18];
    const float* Whl     = (const float*)d_in[19];
    const float* bhl     = (const float*)d_in[20];
    const float* bias_z  = (const float*)d_in[21];
    const float* bias_r  = (const float*)d_in[22];
    const float* bias_h  = (const float*)d_in[23];
    const float* Wag     = (const float*)d_in[24];
    const float* bag     = (const float*)d_in[25];
    const float* Wae     = (const float*)d_in[26];
    const float* bae     = (const float*)d_in[27];
    const float* Wm1     = (const float*)d_in[28];
    const float* bm1     = (const float*)d_in[29];
    const float* Wm2     = (const float*)d_in[30];
    const float* bm2     = (const float*)d_in[31];
    float* out = (float*)d_out;

    const int N = in_sizes[0] / D;
    const int E = in_sizes[1] / 2;
    const size_t ND = (size_t)N * D;

    // workspace layout
    char* ws = (char*)d_ws;
    float* h_buf = (float*)ws;                ws += ND * 4;
    float* t_buf = (float*)ws;                ws += ND * 4;
    float* m_buf = (float*)ws;                ws += ND * 4;
    float* z_buf = (float*)ws;                ws += ND * 4;
    int*   cnt     = (int*)ws;                ws += (size_t)N * 4;
    int*   row_ptr = (int*)ws;                ws += (size_t)(N + 1) * 4 + 12;
    int*   cursor  = (int*)ws;                ws += (size_t)N * 4;
    int*   src_s   = (int*)ws;                ws += (size_t)E * 4;
    float* ew_s    = (float*)ws;              ws += (size_t)E * 4;
    float* bz  = (float*)ws;                  ws += D * 4;
    float* br  = (float*)ws;                  ws += D * 4;
    float* bci = (float*)ws;                  ws += D * 4;
    int* gstart = (int*)ws;                   ws += NGRAPHS * 4;
    int* gend   = (int*)ws;                   ws += NGRAPHS * 4;
    float* pmax = (float*)ws;                 ws += NGRAPHS * D * 4;
    float* psum = (float*)ws;                 ws += NGRAPHS * D * 4;
    unsigned short* wfrag = (unsigned short*)ws;  ws += 10 * 32768 * 2;

    const unsigned short* wfWa  = wfrag + 0 * 32768;
    const unsigned short* wfZm  = wfrag + 1 * 32768;
    const unsigned short* wfZs  = wfrag + 2 * 32768;
    const unsigned short* wfRm  = wfrag + 3 * 32768;
    const unsigned short* wfRs  = wfrag + 4 * 32768;
    const unsigned short* wfHm  = wfrag + 5 * 32768;
    const unsigned short* wfHs  = wfrag + 6 * 32768;
    const unsigned short* wfHg  = wfrag + 7 * 32768;
    const unsigned short* wfHl  = wfrag + 8 * 32768;
    const unsigned short* wfAe  = wfrag + 9 * 32768;

    // h = x
    hipMemcpyAsync(h_buf, x, ND * 4, hipMemcpyDeviceToDevice, stream);

    // weight frag prep (bf16 hi/lo, frag-ordered)
    wprep_kernel<<<10, 256, 0, stream>>>(Wa, Wzm, Wzs, Wrm, Wrs, Whm, Whs, Whg, Whl, Wae, wfrag);

    // CSR build (deterministic recompute each call)
    hipMemsetAsync(cnt, 0, (size_t)N * 4, stream);
    count_kernel<<<(E + 255) / 256, 256, 0, stream>>>(ei, cnt, E);
    scan_kernel<<<1, 1024, 0, stream>>>(cnt, row_ptr, cursor, N);
    scatter_kernel<<<(E + 255) / 256, 256, 0, stream>>>(ei, ew, cursor, src_s, ew_s, E);

    biaspack_kernel<<<1, 128, 0, stream>>>(bzm, bzs, bias_z, brm, brs, bias_r,
                                           bhm, bhs, bias_h, bz, br, bci);

    dim3 aggGrid((N + 1) / 2), aggBlk(256);

    for (int layer = 0; layer < 3; ++layer) {
        // t = h @ Wa
        launch_gemm(0, h_buf, wfWa, nullptr, nullptr, t_buf, N, nullptr, nullptr, nullptr, nullptr, stream);
        // m = aggregate(t)
        agg_kernel<<<aggGrid, aggBlk, 0, stream>>>(t_buf, m_buf, row_ptr, src_s, ew_s, N);
        // z = sigmoid(m@Wzm + h@Wzs + bz)
        launch_gemm(1, m_buf, wfZm, h_buf, wfZs, z_buf, N, bz, nullptr, nullptr, nullptr, stream);
        // rh = sigmoid(m@Wrm + h@Wrs + br) * h   -> t_buf
        launch_gemm(2, m_buf, wfRm, h_buf, wfRs, t_buf, N, br, h_buf, nullptr, nullptr, stream);
        // ci = m@Whm + rh@Whs + bci  -> m_buf (block-row local, in-place safe)
        launch_gemm(3, m_buf, wfHm, t_buf, wfHs, m_buf, N, bci, nullptr, nullptr, nullptr, stream);
        // g = sigmoid(ci@Whg + bhg)  -> t_buf
        launch_gemm(1, m_buf, wfHg, nullptr, nullptr, t_buf, N, bhg, nullptr, nullptr, nullptr, stream);
        // h = z*((ci@Whl + bhl)*g) + (1-z)*h
        launch_gemm(5, m_buf, wfHl, nullptr, nullptr, h_buf, N, bhl, t_buf, z_buf, h_buf, stream);
    }

    // head
    att_kernel<<<(N + 3) / 4, 256, 0, stream>>>(h_buf, Wag, bag, t_buf, N);
    launch_gemm(4, t_buf, wfAe, nullptr, nullptr, m_buf, N, bae, nullptr, nullptr, nullptr, stream);

    hipMemsetAsync(gstart, 0, NGRAPHS * 4, stream);
    hipMemsetAsync(gend, 0, NGRAPHS * 4, stream);
    hipMemsetAsync(pmax, 0, NGRAPHS * D * 4, stream);
    hipMemsetAsync(psum, 0, NGRAPHS * D * 4, stream);
    bounds_kernel<<<(N + 255) / 256, 256, 0, stream>>>(batch, gstart, gend, N);
    dim3 pg(NGRAPHS, PSPLIT);
    pool2_kernel<<<pg, 128, 0, stream>>>(m_buf, gstart, gend, pmax, psum);
    mlp_kernel<<<NGRAPHS, 256, 0, stream>>>(pmax, psum, gstart, gend, Wm1, bm1, Wm2, bm2, out);
}

// Round 3
// 953.687 us; speedup vs baseline: 1.5553x; 1.0828x over previous
//
#include <hip/hip_runtime.h>
#include <hip/hip_bf16.h>

#define D 128
#define NGRAPHS 64
#define PSPLIT 16

typedef short short8 __attribute__((ext_vector_type(8)));
typedef float f32x4 __attribute__((ext_vector_type(4)));

__device__ __forceinline__ float sigf(float x) { return 1.0f / (1.0f + __expf(-x)); }

__device__ __forceinline__ unsigned short f2bf(float x) {
    unsigned u = __float_as_uint(x);
    return (unsigned short)((u + 0x7fffu + ((u >> 16) & 1u)) >> 16);
}
__device__ __forceinline__ float bf2f(unsigned short u) {
    return __uint_as_float(((unsigned)u) << 16);
}
__device__ __forceinline__ void splitf(float x, unsigned short& hb, unsigned short& lb) {
    hb = f2bf(x);
    lb = f2bf(x - bf2f(hb));
}

// ---------------- weight prep: f32 [128][128] -> frag-ordered bf16 hi/lo ----------------
// frag index f = ((j*4 + t)*64 + lane)*8 + s  maps to  W[t*32 + (lane>>4)*8 + s][j*16 + (lane&15)]
__global__ void wprep_kernel(const float* w0, const float* w1, const float* w2,
                             const float* w3, const float* w4, const float* w5,
                             const float* w6, const float* w7, const float* w8,
                             const float* w9, unsigned short* out) {
    const float* ws[10] = {w0, w1, w2, w3, w4, w5, w6, w7, w8, w9};
    const float* W = ws[blockIdx.x];
    unsigned short* oh = out + (size_t)blockIdx.x * 32768;
    unsigned short* ol = oh + 16384;
    for (int f = threadIdx.x; f < 16384; f += 256) {
        int s = f & 7;
        int lane = (f >> 3) & 63;
        int t = (f >> 9) & 3;
        int j = f >> 11;
        int k = t * 32 + ((lane >> 4) << 3) + s;
        int c = (j << 4) + (lane & 15);
        unsigned short hb, lb;
        splitf(W[k * 128 + c], hb, lb);
        oh[f] = hb;
        ol[f] = lb;
    }
}

// ---------------- fused MFMA GEMM over bf16 hi/lo planes ----------------
// MODE 0: C = A0@W  (f32 out, no bias)                      [t = h@Wa]
// MODE 1: ZR fused: z = sig(m@Wzm + h@Wzs + b0) -> C f32;
//         rh = sig(m@Wrm + h@Wrs + b1) * h -> planes         [aux = h planes]
// MODE 2: CI: v = m@Whm + rh@Whs + b0 -> planes
// MODE 3: GH fused: g = sig(ci@Whg + b0); ht = (ci@Whl + b1)*g;
//         h = z*ht + (1-z)*h_old -> planes                   [auxf = z, aux = h planes]
// MODE 4: relu(A0@W + b0) -> C f32                           [att emb]
template <int MODE>
__launch_bounds__(256)
__global__ void gmm(const unsigned short* __restrict__ A0h, const unsigned short* __restrict__ A0l,
                    const unsigned short* __restrict__ A1h, const unsigned short* __restrict__ A1l,
                    const unsigned short* __restrict__ WA0, const unsigned short* __restrict__ WB0,
                    const unsigned short* __restrict__ WA1, const unsigned short* __restrict__ WB1,
                    float* __restrict__ C, unsigned short* __restrict__ Ph, unsigned short* __restrict__ Pl,
                    int N, const float* __restrict__ bias0, const float* __restrict__ bias1,
                    const float* __restrict__ auxf,
                    const unsigned short* __restrict__ auxh, const unsigned short* __restrict__ auxl) {
    constexpr bool DUAL = (MODE == 1 || MODE == 3);
    constexpr int NP = (MODE == 1 || MODE == 2) ? 2 : 1;
    constexpr int RT = DUAL ? 1 : 2;   // row-tiles per wave
    const int tid = threadIdx.x;
    const int wave = tid >> 6;
    const int lane = tid & 63;
    const int r0 = blockIdx.x * (64 * RT) + wave * (16 * RT);

    f32x4 accA[RT][8];
    f32x4 accB[RT][8];
#pragma unroll
    for (int rt = 0; rt < RT; ++rt)
#pragma unroll
        for (int j = 0; j < 8; ++j) {
            accA[rt][j] = (f32x4){0.f, 0.f, 0.f, 0.f};
            accB[rt][j] = (f32x4){0.f, 0.f, 0.f, 0.f};
        }

    int arow[RT];
#pragma unroll
    for (int rt = 0; rt < RT; ++rt) {
        int r = r0 + rt * 16 + (lane & 15);
        arow[rt] = (r < N) ? r : (N - 1);   // clamped rows never stored
    }
    const int kofs = (lane >> 4) << 3;

#pragma unroll
    for (int p = 0; p < NP; ++p) {
        const unsigned short* __restrict__ Ah = p ? A1h : A0h;
        const unsigned short* __restrict__ Al = p ? A1l : A0l;
        const unsigned short* __restrict__ Wa = p ? WA1 : WA0;
        const unsigned short* __restrict__ Wb = p ? WB1 : WB0;
#pragma unroll
        for (int t = 0; t < 4; ++t) {
            short8 ah[RT], al[RT];
#pragma unroll
            for (int rt = 0; rt < RT; ++rt) {
                size_t ab = (size_t)arow[rt] * D + t * 32 + kofs;
                ah[rt] = *(const short8*)(Ah + ab);
                al[rt] = *(const short8*)(Al + ab);
            }
#pragma unroll
            for (int j = 0; j < 8; ++j) {
                const unsigned short* bp = Wa + ((((j << 2) + t) << 6) + lane) * 8;
                short8 bh = *(const short8*)bp;
                short8 bl = *(const short8*)(bp + 16384);
#pragma unroll
                for (int rt = 0; rt < RT; ++rt) {
                    accA[rt][j] = __builtin_amdgcn_mfma_f32_16x16x32_bf16(ah[rt], bh, accA[rt][j], 0, 0, 0);
                    accA[rt][j] = __builtin_amdgcn_mfma_f32_16x16x32_bf16(al[rt], bh, accA[rt][j], 0, 0, 0);
                    accA[rt][j] = __builtin_amdgcn_mfma_f32_16x16x32_bf16(ah[rt], bl, accA[rt][j], 0, 0, 0);
                }
                if (DUAL) {
                    const unsigned short* bp2 = Wb + ((((j << 2) + t) << 6) + lane) * 8;
                    short8 bh2 = *(const short8*)bp2;
                    short8 bl2 = *(const short8*)(bp2 + 16384);
#pragma unroll
                    for (int rt = 0; rt < RT; ++rt) {
                        accB[rt][j] = __builtin_amdgcn_mfma_f32_16x16x32_bf16(ah[rt], bh2, accB[rt][j], 0, 0, 0);
                        accB[rt][j] = __builtin_amdgcn_mfma_f32_16x16x32_bf16(al[rt], bh2, accB[rt][j], 0, 0, 0);
                        accB[rt][j] = __builtin_amdgcn_mfma_f32_16x16x32_bf16(ah[rt], bl2, accB[rt][j], 0, 0, 0);
                    }
                }
            }
        }
    }

    // C/D layout (HW-verified): col = lane&15, row = (lane>>4)*4 + reg
    const int col0 = lane & 15;
    const int rb = (lane >> 4) << 2;
#pragma unroll
    for (int rt = 0; rt < RT; ++rt)
#pragma unroll
        for (int j = 0; j < 8; ++j) {
            int col = (j << 4) + col0;
#pragma unroll
            for (int reg = 0; reg < 4; ++reg) {
                int grow = r0 + rt * 16 + rb + reg;
                if (grow >= N) continue;
                size_t o = (size_t)grow * D + col;
                float vA = accA[rt][j][reg];
                if (MODE == 0) {
                    C[o] = vA;
                } else if (MODE == 1) {
                    float z = sigf(vA + bias0[col]);
                    C[o] = z;
                    float r = sigf(accB[rt][j][reg] + bias1[col]);
                    float hv = bf2f(auxh[o]) + bf2f(auxl[o]);
                    unsigned short hb, lb;
                    splitf(r * hv, hb, lb);
                    Ph[o] = hb; Pl[o] = lb;
                } else if (MODE == 2) {
                    unsigned short hb, lb;
                    splitf(vA + bias0[col], hb, lb);
                    Ph[o] = hb; Pl[o] = lb;
                } else if (MODE == 3) {
                    float g = sigf(vA + bias0[col]);
                    float ht = (accB[rt][j][reg] + bias1[col]) * g;
                    float z = auxf[o];
                    float hv = bf2f(auxh[o]) + bf2f(auxl[o]);
                    float v = z * ht + (1.f - z) * hv;
                    unsigned short hb, lb;
                    splitf(v, hb, lb);
                    Ph[o] = hb; Pl[o] = lb;
                } else {
                    C[o] = fmaxf(vA + bias0[col], 0.f);
                }
            }
        }
}

// ---------------- initial split: x -> h planes ----------------
__global__ void split0_kernel(const float* __restrict__ x, unsigned short* __restrict__ hh,
                              unsigned short* __restrict__ hl, int ND4) {
    int i = blockIdx.x * 256 + threadIdx.x;
    if (i >= ND4) return;
    float4 v = ((const float4*)x)[i];
    float vv[4] = {v.x, v.y, v.z, v.w};
    unsigned short hb[4], lb[4];
#pragma unroll
    for (int k = 0; k < 4; ++k) splitf(vv[k], hb[k], lb[k]);
    unsigned long long uh = (unsigned long long)hb[0] | ((unsigned long long)hb[1] << 16) |
                            ((unsigned long long)hb[2] << 32) | ((unsigned long long)hb[3] << 48);
    unsigned long long ul = (unsigned long long)lb[0] | ((unsigned long long)lb[1] << 16) |
                            ((unsigned long long)lb[2] << 32) | ((unsigned long long)lb[3] << 48);
    ((unsigned long long*)hh)[i] = uh;
    ((unsigned long long*)hl)[i] = ul;
}

// ---------------- CSR build ----------------
__global__ void count_kernel(const int* __restrict__ ei, int* __restrict__ cnt, int E) {
    int e = blockIdx.x * 256 + threadIdx.x;
    if (e < E) atomicAdd(&cnt[ei[E + e]], 1);
}

__global__ void scan1_kernel(const int* __restrict__ cnt, int* __restrict__ exc,
                             int* __restrict__ partial, int N) {
    __shared__ int sd[1024];
    int tid = threadIdx.x;
    int base = blockIdx.x * 4096;
    int v[4], s = 0;
#pragma unroll
    for (int i = 0; i < 4; ++i) {
        int idx = base + tid * 4 + i;
        v[i] = (idx < N) ? cnt[idx] : 0;
        s += v[i];
    }
    sd[tid] = s;
    __syncthreads();
    for (int off = 1; off < 1024; off <<= 1) {
        int add = (tid >= off) ? sd[tid - off] : 0;
        __syncthreads();
        sd[tid] += add;
        __syncthreads();
    }
    int ex = sd[tid] - s;
#pragma unroll
    for (int i = 0; i < 4; ++i) {
        int idx = base + tid * 4 + i;
        if (idx < N) exc[idx] = ex;
        ex += v[i];
    }
    if (tid == 1023) partial[blockIdx.x] = sd[1023];
}

__global__ void scan2_kernel(int* __restrict__ partial, int nb) {
    __shared__ int sd[64];
    int tid = threadIdx.x;
    int v = (tid < nb) ? partial[tid] : 0;
    sd[tid] = v;
    __syncthreads();
    for (int off = 1; off < 64; off <<= 1) {
        int add = (tid >= off) ? sd[tid - off] : 0;
        __syncthreads();
        sd[tid] += add;
        __syncthreads();
    }
    if (tid < nb) partial[tid] = sd[tid] - v;
}

__global__ void scan3_kernel(int* __restrict__ row_ptr, const int* __restrict__ partial,
                             int* __restrict__ cursor, int N, int E) {
    int i = blockIdx.x * 256 + threadIdx.x;
    if (i < N) {
        int v = row_ptr[i] + partial[i >> 12];
        row_ptr[i] = v;
        cursor[i] = v;
    }
    if (i == 0) row_ptr[N] = E;
}

__global__ void scatter_kernel(const int* __restrict__ ei, const float* __restrict__ ew,
                               int* __restrict__ cursor, int* __restrict__ src_s,
                               float* __restrict__ ew_s, int E) {
    int e = blockIdx.x * 256 + threadIdx.x;
    if (e < E) {
        int d = ei[E + e];
        int pos = atomicAdd(&cursor[d], 1);
        src_s[pos] = ei[e];
        ew_s[pos] = ew[e];
    }
}

// ---------------- aggregation: m = t[n] + sum w_e * t[src_e], split-write ----------------
__global__ void agg_kernel(const float* __restrict__ t,
                           unsigned short* __restrict__ mh, unsigned short* __restrict__ ml,
                           const int* __restrict__ row_ptr, const int* __restrict__ src_s,
                           const float* __restrict__ ew_s, int N) {
    int n = blockIdx.x * 8 + (threadIdx.x >> 5);
    int c4 = threadIdx.x & 31;          // float4 index within row
    if (n >= N) return;
    const float4* tp = (const float4*)t;
    float4 a = tp[n * 32 + c4];
    float ax = a.x, ay = a.y, az = a.z, aw = a.w;
    int e0 = row_ptr[n], e1 = row_ptr[n + 1];
    int e = e0;
    for (; e + 4 <= e1; e += 4) {
        int s0 = src_s[e], s1 = src_s[e + 1], s2 = src_s[e + 2], s3 = src_s[e + 3];
        float w0 = ew_s[e], w1 = ew_s[e + 1], w2 = ew_s[e + 2], w3 = ew_s[e + 3];
        float4 v0 = tp[s0 * 32 + c4];
        float4 v1 = tp[s1 * 32 + c4];
        float4 v2 = tp[s2 * 32 + c4];
        float4 v3 = tp[s3 * 32 + c4];
        ax += w0 * v0.x + w1 * v1.x + w2 * v2.x + w3 * v3.x;
        ay += w0 * v0.y + w1 * v1.y + w2 * v2.y + w3 * v3.y;
        az += w0 * v0.z + w1 * v1.z + w2 * v2.z + w3 * v3.z;
        aw += w0 * v0.w + w1 * v1.w + w2 * v2.w + w3 * v3.w;
    }
    for (; e < e1; ++e) {
        int s = src_s[e];
        float w = ew_s[e];
        float4 v = tp[s * 32 + c4];
        ax += w * v.x; ay += w * v.y; az += w * v.z; aw += w * v.w;
    }
    float vv[4] = {ax, ay, az, aw};
    unsigned short hb[4], lb[4];
#pragma unroll
    for (int k = 0; k < 4; ++k) splitf(vv[k], hb[k], lb[k]);
    size_t i8 = (size_t)n * 32 + c4;
    unsigned long long uh = (unsigned long long)hb[0] | ((unsigned long long)hb[1] << 16) |
                            ((unsigned long long)hb[2] << 32) | ((unsigned long long)hb[3] << 48);
    unsigned long long ul = (unsigned long long)lb[0] | ((unsigned long long)lb[1] << 16) |
                            ((unsigned long long)lb[2] << 32) | ((unsigned long long)lb[3] << 48);
    ((unsigned long long*)mh)[i8] = uh;
    ((unsigned long long*)ml)[i8] = ul;
}

// ---------------- bias pack ----------------
__global__ void biaspack_kernel(const float* bzm, const float* bzs, const float* bz0,
                                const float* brm, const float* brs, const float* br0,
                                const float* bhm, const float* bhs, const float* bh0,
                                float* bz, float* br, float* bci) {
    int i = threadIdx.x;
    if (i < D) {
        bz[i] = bzm[i] + bzs[i] + bz0[i];
        br[i] = brm[i] + brs[i] + br0[i];
        bci[i] = bhm[i] + bhs[i] + bh0[i];
    }
}

// ---------------- head: hA = h * sigmoid(h@Wg + bg), split-write ----------------
__global__ void att_kernel(const unsigned short* __restrict__ hh, const unsigned short* __restrict__ hl,
                           const float* __restrict__ Wg, const float* __restrict__ bg,
                           unsigned short* __restrict__ oh, unsigned short* __restrict__ ol, int N) {
    int w = threadIdx.x >> 6, l = threadIdx.x & 63;
    int n = blockIdx.x * 4 + w;
    if (n >= N) return;
    size_t base = (size_t)n * D;
    float h0 = bf2f(hh[base + l]) + bf2f(hl[base + l]);
    float h1 = bf2f(hh[base + 64 + l]) + bf2f(hl[base + 64 + l]);
    float p = h0 * Wg[l] + h1 * Wg[64 + l];
#pragma unroll
    for (int off = 32; off; off >>= 1) p += __shfl_xor(p, off);
    float att = sigf(p + bg[0]);
    unsigned short hb, lb;
    splitf(h0 * att, hb, lb);
    oh[base + l] = hb; ol[base + l] = lb;
    splitf(h1 * att, hb, lb);
    oh[base + 64 + l] = hb; ol[base + 64 + l] = lb;
}

__global__ void bounds_kernel(const int* __restrict__ batch, int* __restrict__ gstart,
                              int* __restrict__ gend, int N) {
    int i = blockIdx.x * 256 + threadIdx.x;
    if (i >= N) return;
    int b = batch[i];
    if (i == 0 || batch[i - 1] != b) gstart[b] = i;
    if (i == N - 1 || batch[i + 1] != b) gend[b] = i + 1;
}

__global__ void pool2_kernel(const float* __restrict__ ha, const int* __restrict__ gstart,
                             const int* __restrict__ gend, float* __restrict__ pmax,
                             float* __restrict__ psum) {
    int g = blockIdx.x;
    int slice = blockIdx.y;
    int c = threadIdx.x;
    int s = gstart[g], e = gend[g];
    float vmax = 0.f, vsum = 0.f;
    for (int n = s + slice; n < e; n += PSPLIT) {
        float v = ha[(size_t)n * D + c];
        vmax = fmaxf(vmax, v);
        vsum += v;
    }
    atomicMax((int*)&pmax[g * D + c], __float_as_int(vmax));   // ha >= 0
    atomicAdd(&psum[g * D + c], vsum);
}

__global__ void mlp_kernel(const float* __restrict__ pmax, const float* __restrict__ psum,
                           const int* __restrict__ gstart, const int* __restrict__ gend,
                           const float* __restrict__ W1, const float* __restrict__ b1,
                           const float* __restrict__ W2, const float* __restrict__ b2,
                           float* __restrict__ out) {
    __shared__ float hid[128];
    __shared__ float pg[256];
    int g = blockIdx.x, tid = threadIdx.x;
    int cnt = max(gend[g] - gstart[g], 1);
    if (tid < 128) pg[tid] = pmax[g * D + tid];
    else pg[tid] = psum[g * D + (tid - 128)] / (float)cnt;
    __syncthreads();
    if (tid < 128) {
        float acc = b1[tid];
        for (int k = 0; k < 256; k++) acc += pg[k] * W1[k * 128 + tid];
        hid[tid] = fmaxf(acc, 0.f);
    }
    __syncthreads();
    if (tid < 16) {
        float acc = b2[tid];
        for (int k = 0; k < 128; k++) acc += hid[k] * W2[k * 16 + tid];
        out[g * 16 + tid] = acc;
    }
}

// ---------------- host ----------------
extern "C" void kernel_launch(void* const* d_in, const int* in_sizes, int n_in,
                              void* d_out, int out_size, void* d_ws, size_t ws_size,
                              hipStream_t stream) {
    const float* x       = (const float*)d_in[0];
    const int*   ei      = (const int*)d_in[1];
    const int*   batch   = (const int*)d_in[2];
    const float* ew      = (const float*)d_in[3];
    const float* Wa      = (const float*)d_in[4];
    const float* Wzm     = (const float*)d_in[5];
    const float* bzm     = (const float*)d_in[6];
    const float* Wzs     = (const float*)d_in[7];
    const float* bzs     = (const float*)d_in[8];
    const float* Wrm     = (const float*)d_in[9];
    const float* brm     = (const float*)d_in[10];
    const float* Wrs     = (const float*)d_in[11];
    const float* brs     = (const float*)d_in[12];
    const float* Whm     = (const float*)d_in[13];
    const float* bhm     = (const float*)d_in[14];
    const float* Whs     = (const float*)d_in[15];
    const float* bhs     = (const float*)d_in[16];
    const float* Whg     = (const float*)d_in[17];
    const float* bhg     = (const float*)d_in[18];
    const float* Whl     = (const float*)d_in[19];
    const float* bhl     = (const float*)d_in[20];
    const float* bias_z  = (const float*)d_in[21];
    const float* bias_r  = (const float*)d_in[22];
    const float* bias_h  = (const float*)d_in[23];
    const float* Wag     = (const float*)d_in[24];
    const float* bag     = (const float*)d_in[25];
    const float* Wae     = (const float*)d_in[26];
    const float* bae     = (const float*)d_in[27];
    const float* Wm1     = (const float*)d_in[28];
    const float* bm1     = (const float*)d_in[29];
    const float* Wm2     = (const float*)d_in[30];
    const float* bm2     = (const float*)d_in[31];
    float* out = (float*)d_out;

    const int N = in_sizes[0] / D;
    const int E = in_sizes[1] / 2;
    const size_t ND = (size_t)N * D;

    // workspace layout (~108 MB)
    char* p = (char*)d_ws;
    unsigned short* h_hi = (unsigned short*)p;   p += ND * 4;           // hi + lo contiguous
    unsigned short* h_lo = h_hi + ND;
    float* tz = (float*)p;                       p += ND * 4;           // t, then z; att planes at head
    unsigned short* m_hi = (unsigned short*)p;   p += ND * 4;           // m, then ci (in-place)
    unsigned short* m_lo = m_hi + ND;
    unsigned short* rh_hi = (unsigned short*)p;  p += ND * 4;           // rh; emb-out f32 at head
    unsigned short* rh_lo = rh_hi + ND;
    int* cnt      = (int*)p;                     p += (size_t)N * 4;
    int* row_ptr  = (int*)p;                     p += (size_t)(N + 2) * 4 + 8;
    int* cursor   = (int*)p;                     p += (size_t)N * 4;
    int* partial  = (int*)p;                     p += 64 * 4;
    int* src_s    = (int*)p;                     p += (size_t)E * 4;
    float* ew_s   = (float*)p;                   p += (size_t)E * 4;
    float* bz     = (float*)p;                   p += D * 4;
    float* br     = (float*)p;                   p += D * 4;
    float* bci    = (float*)p;                   p += D * 4;
    int* gstart   = (int*)p;                     p += NGRAPHS * 4;
    int* gend     = (int*)p;                     p += NGRAPHS * 4;
    float* pmax   = (float*)p;                   p += NGRAPHS * D * 4;
    float* psum   = (float*)p;                   p += NGRAPHS * D * 4;
    unsigned short* wfrag = (unsigned short*)p;  p += 10 * 32768 * 2;

    const unsigned short* wfWa = wfrag + 0 * 32768;
    const unsigned short* wfZm = wfrag + 1 * 32768;
    const unsigned short* wfZs = wfrag + 2 * 32768;
    const unsigned short* wfRm = wfrag + 3 * 32768;
    const unsigned short* wfRs = wfrag + 4 * 32768;
    const unsigned short* wfHm = wfrag + 5 * 32768;
    const unsigned short* wfHs = wfrag + 6 * 32768;
    const unsigned short* wfHg = wfrag + 7 * 32768;
    const unsigned short* wfHl = wfrag + 8 * 32768;
    const unsigned short* wfAe = wfrag + 9 * 32768;

    // views for head stage
    unsigned short* at_hi = (unsigned short*)tz;        // att output planes reuse t/z space
    unsigned short* at_lo = at_hi + ND;
    float* embf = (float*)rh_hi;                        // emb output f32 reuses rh space

    const int gD = (N + 127) / 128;   // single-out gemm grid (RT=2)
    const int gS = (N + 63) / 64;     // dual-out gemm grid (RT=1)

    // h planes = split(x)
    split0_kernel<<<(int)((ND / 4 + 255) / 256), 256, 0, stream>>>(x, h_hi, h_lo, (int)(ND / 4));

    // weight frag prep
    wprep_kernel<<<10, 256, 0, stream>>>(Wa, Wzm, Wzs, Wrm, Wrs, Whm, Whs, Whg, Whl, Wae, wfrag);

    // CSR build
    hipMemsetAsync(cnt, 0, (size_t)N * 4, stream);
    count_kernel<<<(E + 255) / 256, 256, 0, stream>>>(ei, cnt, E);
    int nb = (N + 4095) / 4096;
    scan1_kernel<<<nb, 1024, 0, stream>>>(cnt, row_ptr, partial, N);
    scan2_kernel<<<1, 64, 0, stream>>>(partial, nb);
    scan3_kernel<<<(N + 255) / 256, 256, 0, stream>>>(row_ptr, partial, cursor, N, E);
    scatter_kernel<<<(E + 255) / 256, 256, 0, stream>>>(ei, ew, cursor, src_s, ew_s, E);

    biaspack_kernel<<<1, 128, 0, stream>>>(bzm, bzs, bias_z, brm, brs, bias_r,
                                           bhm, bhs, bias_h, bz, br, bci);

    for (int layer = 0; layer < 3; ++layer) {
        // t = h @ Wa  (f32)
        gmm<0><<<gD, 256, 0, stream>>>(h_hi, h_lo, nullptr, nullptr, wfWa, nullptr, nullptr, nullptr,
                                       tz, nullptr, nullptr, N, nullptr, nullptr, nullptr, nullptr, nullptr);
        // m = aggregate(t) -> planes
        agg_kernel<<<(N + 7) / 8, 256, 0, stream>>>(tz, m_hi, m_lo, row_ptr, src_s, ew_s, N);
        // z (f32 -> tz) and rh (planes) fused
        gmm<1><<<gS, 256, 0, stream>>>(m_hi, m_lo, h_hi, h_lo, wfZm, wfRm, wfZs, wfRs,
                                       tz, rh_hi, rh_lo, N, bz, br, nullptr, h_hi, h_lo);
        // ci = m@Whm + rh@Whs + bci -> planes (in-place over m)
        gmm<2><<<gD, 256, 0, stream>>>(m_hi, m_lo, rh_hi, rh_lo, wfHm, nullptr, wfHs, nullptr,
                                       nullptr, m_hi, m_lo, N, bci, nullptr, nullptr, nullptr, nullptr);
        // h = z*((ci@Whl + bhl)*sig(ci@Whg + bhg)) + (1-z)*h -> planes (in-place over h)
        gmm<3><<<gS, 256, 0, stream>>>(m_hi, m_lo, nullptr, nullptr, wfHg, wfHl, nullptr, nullptr,
                                       nullptr, h_hi, h_lo, N, bhg, bhl, tz, h_hi, h_lo);
    }

    // head
    att_kernel<<<(N + 3) / 4, 256, 0, stream>>>(h_hi, h_lo, Wag, bag, at_hi, at_lo, N);
    gmm<4><<<gD, 256, 0, stream>>>(at_hi, at_lo, nullptr, nullptr, wfAe, nullptr, nullptr, nullptr,
                                   embf, nullptr, nullptr, N, bae, nullptr, nullptr, nullptr, nullptr);

    hipMemsetAsync(gstart, 0, NGRAPHS * 4, stream);
    hipMemsetAsync(gend, 0, NGRAPHS * 4, stream);
    hipMemsetAsync(pmax, 0, NGRAPHS * D * 4, stream);
    hipMemsetAsync(psum, 0, NGRAPHS * D * 4, stream);
    bounds_kernel<<<(N + 255) / 256, 256, 0, stream>>>(batch, gstart, gend, N);
    dim3 pg(NGRAPHS, PSPLIT);
    pool2_kernel<<<pg, 128, 0, stream>>>(embf, gstart, gend, pmax, psum);
    mlp_kernel<<<NGRAPHS, 256, 0, stream>>>(pmax, psum, gstart, gend, Wm1, bm1, Wm2, bm2, out);
}

// Round 4
// 787.880 us; speedup vs baseline: 1.8826x; 1.2104x over previous
//
#include <hip/hip_runtime.h>
#include <hip/hip_bf16.h>

#define D 128
#define NGRAPHS 64
#define PSPLIT 16

typedef short short8 __attribute__((ext_vector_type(8)));
typedef float f32x4 __attribute__((ext_vector_type(4)));

__device__ __forceinline__ float sigf(float x) { return 1.0f / (1.0f + __expf(-x)); }

__device__ __forceinline__ unsigned short f2bf(float x) {
    unsigned u = __float_as_uint(x);
    return (unsigned short)((u + 0x7fffu + ((u >> 16) & 1u)) >> 16);
}
__device__ __forceinline__ float bf2f(unsigned short u) {
    return __uint_as_float(((unsigned)u) << 16);
}
__device__ __forceinline__ void splitf(float x, unsigned short& hb, unsigned short& lb) {
    hb = f2bf(x);
    lb = f2bf(x - bf2f(hb));
}

// ---------------- weight prep: f32 [128][128] -> frag-ordered bf16 hi/lo ----------------
// frag index f = ((j*4 + t)*64 + lane)*8 + s  maps to  W[t*32 + (lane>>4)*8 + s][j*16 + (lane&15)]
__global__ void wprep_kernel(const float* w0, const float* w1, const float* w2,
                             const float* w3, const float* w4, const float* w5,
                             const float* w6, const float* w7, const float* w8,
                             const float* w9, unsigned short* out) {
    const float* ws[10] = {w0, w1, w2, w3, w4, w5, w6, w7, w8, w9};
    const float* W = ws[blockIdx.x];
    unsigned short* oh = out + (size_t)blockIdx.x * 32768;
    unsigned short* ol = oh + 16384;
    for (int f = threadIdx.x; f < 16384; f += 256) {
        int s = f & 7;
        int lane = (f >> 3) & 63;
        int t = (f >> 9) & 3;
        int j = f >> 11;
        int k = t * 32 + ((lane >> 4) << 3) + s;
        int c = (j << 4) + (lane & 15);
        unsigned short hb, lb;
        splitf(W[k * 128 + c], hb, lb);
        oh[f] = hb;
        ol[f] = lb;
    }
}

// ---------------- fused MFMA GEMM over bf16 hi/lo planes, column-split ----------------
// Tile: 64 rows x (NJ*16) cols per block; grid = (ceil(N/64), 8/NJ). 4 waves, 16 rows each.
// MODE 0: C = A0@W  (f32 out, no bias)                      [t = h@Wa]
// MODE 1: ZR fused: z = sig(m@Wzm + h@Wzs + b0) -> C f32;
//         rh = sig(m@Wrm + h@Wrs + b1) * h -> planes         [aux = h planes]
// MODE 2: CI: v = m@Whm + rh@Whs + b0 -> planes
// MODE 3: GH fused: g = sig(ci@Whg + b0); ht = (ci@Whl + b1)*g;
//         h = z*ht + (1-z)*h_old -> planes                   [auxf = z, aux = h planes]
// MODE 4: relu(A0@W + b0) -> C f32                           [att emb]
template <int MODE, int NJ>
__launch_bounds__(256)
__global__ void gmm(const unsigned short* __restrict__ A0h, const unsigned short* __restrict__ A0l,
                    const unsigned short* __restrict__ A1h, const unsigned short* __restrict__ A1l,
                    const unsigned short* __restrict__ WA0, const unsigned short* __restrict__ WB0,
                    const unsigned short* __restrict__ WA1, const unsigned short* __restrict__ WB1,
                    float* __restrict__ C, unsigned short* __restrict__ Ph, unsigned short* __restrict__ Pl,
                    int N, const float* __restrict__ bias0, const float* __restrict__ bias1,
                    const float* __restrict__ auxf,
                    const unsigned short* __restrict__ auxh, const unsigned short* __restrict__ auxl) {
    constexpr bool DUAL = (MODE == 1 || MODE == 3);
    constexpr int NP = (MODE == 1 || MODE == 2) ? 2 : 1;
    const int tid = threadIdx.x;
    const int wave = tid >> 6;
    const int lane = tid & 63;
    const int by = blockIdx.y;
    const int r0 = blockIdx.x * 64 + wave * 16;

    f32x4 accA[NJ];
    f32x4 accB[NJ];
#pragma unroll
    for (int j = 0; j < NJ; ++j) {
        accA[j] = (f32x4){0.f, 0.f, 0.f, 0.f};
        accB[j] = (f32x4){0.f, 0.f, 0.f, 0.f};
    }

    int r = r0 + (lane & 15);
    const int arow = (r < N) ? r : (N - 1);   // clamped rows never stored
    const int kofs = (lane >> 4) << 3;

#pragma unroll
    for (int p = 0; p < NP; ++p) {
        const unsigned short* __restrict__ Ah = p ? A1h : A0h;
        const unsigned short* __restrict__ Al = p ? A1l : A0l;
        const unsigned short* __restrict__ Wa = p ? WA1 : WA0;
        const unsigned short* __restrict__ Wb = p ? WB1 : WB0;
#pragma unroll
        for (int t = 0; t < 4; ++t) {
            size_t ab = (size_t)arow * D + t * 32 + kofs;
            short8 ah = *(const short8*)(Ah + ab);
            short8 al = *(const short8*)(Al + ab);
#pragma unroll
            for (int jl = 0; jl < NJ; ++jl) {
                int jg = by * NJ + jl;
                const unsigned short* bp = Wa + ((((jg << 2) + t) << 6) + lane) * 8;
                short8 bh = *(const short8*)bp;
                short8 bl = *(const short8*)(bp + 16384);
                accA[jl] = __builtin_amdgcn_mfma_f32_16x16x32_bf16(ah, bh, accA[jl], 0, 0, 0);
                accA[jl] = __builtin_amdgcn_mfma_f32_16x16x32_bf16(al, bh, accA[jl], 0, 0, 0);
                accA[jl] = __builtin_amdgcn_mfma_f32_16x16x32_bf16(ah, bl, accA[jl], 0, 0, 0);
                if (DUAL) {
                    const unsigned short* bp2 = Wb + ((((jg << 2) + t) << 6) + lane) * 8;
                    short8 bh2 = *(const short8*)bp2;
                    short8 bl2 = *(const short8*)(bp2 + 16384);
                    accB[jl] = __builtin_amdgcn_mfma_f32_16x16x32_bf16(ah, bh2, accB[jl], 0, 0, 0);
                    accB[jl] = __builtin_amdgcn_mfma_f32_16x16x32_bf16(al, bh2, accB[jl], 0, 0, 0);
                    accB[jl] = __builtin_amdgcn_mfma_f32_16x16x32_bf16(ah, bl2, accB[jl], 0, 0, 0);
                }
            }
        }
    }

    // C/D layout (HW-verified): col = lane&15, row = (lane>>4)*4 + reg
    const int col0 = lane & 15;
    const int rb = (lane >> 4) << 2;
#pragma unroll
    for (int jl = 0; jl < NJ; ++jl) {
        int col = ((by * NJ + jl) << 4) + col0;
#pragma unroll
        for (int reg = 0; reg < 4; ++reg) {
            int grow = r0 + rb + reg;
            if (grow >= N) continue;
            size_t o = (size_t)grow * D + col;
            float vA = accA[jl][reg];
            if (MODE == 0) {
                C[o] = vA;
            } else if (MODE == 1) {
                float z = sigf(vA + bias0[col]);
                C[o] = z;
                float rr = sigf(accB[jl][reg] + bias1[col]);
                float hv = bf2f(auxh[o]) + bf2f(auxl[o]);
                unsigned short hb, lb;
                splitf(rr * hv, hb, lb);
                Ph[o] = hb; Pl[o] = lb;
            } else if (MODE == 2) {
                unsigned short hb, lb;
                splitf(vA + bias0[col], hb, lb);
                Ph[o] = hb; Pl[o] = lb;
            } else if (MODE == 3) {
                float g = sigf(vA + bias0[col]);
                float ht = (accB[jl][reg] + bias1[col]) * g;
                float z = auxf[o];
                float hv = bf2f(auxh[o]) + bf2f(auxl[o]);
                float v = z * ht + (1.f - z) * hv;
                unsigned short hb, lb;
                splitf(v, hb, lb);
                Ph[o] = hb; Pl[o] = lb;
            } else {
                C[o] = fmaxf(vA + bias0[col], 0.f);
            }
        }
    }
}

// ---------------- initial split: x -> h planes ----------------
__global__ void split0_kernel(const float* __restrict__ x, unsigned short* __restrict__ hh,
                              unsigned short* __restrict__ hl, int ND4) {
    int i = blockIdx.x * 256 + threadIdx.x;
    if (i >= ND4) return;
    float4 v = ((const float4*)x)[i];
    float vv[4] = {v.x, v.y, v.z, v.w};
    unsigned short hb[4], lb[4];
#pragma unroll
    for (int k = 0; k < 4; ++k) splitf(vv[k], hb[k], lb[k]);
    unsigned long long uh = (unsigned long long)hb[0] | ((unsigned long long)hb[1] << 16) |
                            ((unsigned long long)hb[2] << 32) | ((unsigned long long)hb[3] << 48);
    unsigned long long ul = (unsigned long long)lb[0] | ((unsigned long long)lb[1] << 16) |
                            ((unsigned long long)lb[2] << 32) | ((unsigned long long)lb[3] << 48);
    ((unsigned long long*)hh)[i] = uh;
    ((unsigned long long*)hl)[i] = ul;
}

// ---------------- CSR build ----------------
__global__ void count_kernel(const int* __restrict__ ei, int* __restrict__ cnt, int E) {
    int e = blockIdx.x * 256 + threadIdx.x;
    if (e < E) atomicAdd(&cnt[ei[E + e]], 1);
}

__global__ void scan1_kernel(const int* __restrict__ cnt, int* __restrict__ exc,
                             int* __restrict__ partial, int N) {
    __shared__ int sd[1024];
    int tid = threadIdx.x;
    int base = blockIdx.x * 4096;
    int v[4], s = 0;
#pragma unroll
    for (int i = 0; i < 4; ++i) {
        int idx = base + tid * 4 + i;
        v[i] = (idx < N) ? cnt[idx] : 0;
        s += v[i];
    }
    sd[tid] = s;
    __syncthreads();
    for (int off = 1; off < 1024; off <<= 1) {
        int add = (tid >= off) ? sd[tid - off] : 0;
        __syncthreads();
        sd[tid] += add;
        __syncthreads();
    }
    int ex = sd[tid] - s;
#pragma unroll
    for (int i = 0; i < 4; ++i) {
        int idx = base + tid * 4 + i;
        if (idx < N) exc[idx] = ex;
        ex += v[i];
    }
    if (tid == 1023) partial[blockIdx.x] = sd[1023];
}

__global__ void scan2_kernel(int* __restrict__ partial, int nb) {
    __shared__ int sd[64];
    int tid = threadIdx.x;
    int v = (tid < nb) ? partial[tid] : 0;
    sd[tid] = v;
    __syncthreads();
    for (int off = 1; off < 64; off <<= 1) {
        int add = (tid >= off) ? sd[tid - off] : 0;
        __syncthreads();
        sd[tid] += add;
        __syncthreads();
    }
    if (tid < nb) partial[tid] = sd[tid] - v;
}

__global__ void scan3_kernel(int* __restrict__ row_ptr, const int* __restrict__ partial,
                             int* __restrict__ cursor, int N, int E) {
    int i = blockIdx.x * 256 + threadIdx.x;
    if (i < N) {
        int v = row_ptr[i] + partial[i >> 12];
        row_ptr[i] = v;
        cursor[i] = v;
    }
    if (i == 0) row_ptr[N] = E;
}

__global__ void scatter_kernel(const int* __restrict__ ei, const float* __restrict__ ew,
                               int* __restrict__ cursor, int* __restrict__ src_s,
                               float* __restrict__ ew_s, int E) {
    int e = blockIdx.x * 256 + threadIdx.x;
    if (e < E) {
        int d = ei[E + e];
        int pos = atomicAdd(&cursor[d], 1);
        src_s[pos] = ei[e];
        ew_s[pos] = ew[e];
    }
}

// ---------------- aggregation: m = t[n] + sum w_e * t[src_e], split-write ----------------
__global__ void agg_kernel(const float* __restrict__ t,
                           unsigned short* __restrict__ mh, unsigned short* __restrict__ ml,
                           const int* __restrict__ row_ptr, const int* __restrict__ src_s,
                           const float* __restrict__ ew_s, int N) {
    int n = blockIdx.x * 8 + (threadIdx.x >> 5);
    int c4 = threadIdx.x & 31;          // float4 index within row
    if (n >= N) return;
    const float4* tp = (const float4*)t;
    float4 a = tp[n * 32 + c4];
    float ax = a.x, ay = a.y, az = a.z, aw = a.w;
    int e0 = row_ptr[n], e1 = row_ptr[n + 1];
    int e = e0;
    for (; e + 4 <= e1; e += 4) {
        int s0 = src_s[e], s1 = src_s[e + 1], s2 = src_s[e + 2], s3 = src_s[e + 3];
        float w0 = ew_s[e], w1 = ew_s[e + 1], w2 = ew_s[e + 2], w3 = ew_s[e + 3];
        float4 v0 = tp[s0 * 32 + c4];
        float4 v1 = tp[s1 * 32 + c4];
        float4 v2 = tp[s2 * 32 + c4];
        float4 v3 = tp[s3 * 32 + c4];
        ax += w0 * v0.x + w1 * v1.x + w2 * v2.x + w3 * v3.x;
        ay += w0 * v0.y + w1 * v1.y + w2 * v2.y + w3 * v3.y;
        az += w0 * v0.z + w1 * v1.z + w2 * v2.z + w3 * v3.z;
        aw += w0 * v0.w + w1 * v1.w + w2 * v2.w + w3 * v3.w;
    }
    for (; e < e1; ++e) {
        int s = src_s[e];
        float w = ew_s[e];
        float4 v = tp[s * 32 + c4];
        ax += w * v.x; ay += w * v.y; az += w * v.z; aw += w * v.w;
    }
    float vv[4] = {ax, ay, az, aw};
    unsigned short hb[4], lb[4];
#pragma unroll
    for (int k = 0; k < 4; ++k) splitf(vv[k], hb[k], lb[k]);
    size_t i8 = (size_t)n * 32 + c4;
    unsigned long long uh = (unsigned long long)hb[0] | ((unsigned long long)hb[1] << 16) |
                            ((unsigned long long)hb[2] << 32) | ((unsigned long long)hb[3] << 48);
    unsigned long long ul = (unsigned long long)lb[0] | ((unsigned long long)lb[1] << 16) |
                            ((unsigned long long)lb[2] << 32) | ((unsigned long long)lb[3] << 48);
    ((unsigned long long*)mh)[i8] = uh;
    ((unsigned long long*)ml)[i8] = ul;
}

// ---------------- bias pack ----------------
__global__ void biaspack_kernel(const float* bzm, const float* bzs, const float* bz0,
                                const float* brm, const float* brs, const float* br0,
                                const float* bhm, const float* bhs, const float* bh0,
                                float* bz, float* br, float* bci) {
    int i = threadIdx.x;
    if (i < D) {
        bz[i] = bzm[i] + bzs[i] + bz0[i];
        br[i] = brm[i] + brs[i] + br0[i];
        bci[i] = bhm[i] + bhs[i] + bh0[i];
    }
}

// ---------------- head: hA = h * sigmoid(h@Wg + bg), split-write ----------------
__global__ void att_kernel(const unsigned short* __restrict__ hh, const unsigned short* __restrict__ hl,
                           const float* __restrict__ Wg, const float* __restrict__ bg,
                           unsigned short* __restrict__ oh, unsigned short* __restrict__ ol, int N) {
    int w = threadIdx.x >> 6, l = threadIdx.x & 63;
    int n = blockIdx.x * 4 + w;
    if (n >= N) return;
    size_t base = (size_t)n * D;
    float h0 = bf2f(hh[base + l]) + bf2f(hl[base + l]);
    float h1 = bf2f(hh[base + 64 + l]) + bf2f(hl[base + 64 + l]);
    float p = h0 * Wg[l] + h1 * Wg[64 + l];
#pragma unroll
    for (int off = 32; off; off >>= 1) p += __shfl_xor(p, off);
    float att = sigf(p + bg[0]);
    unsigned short hb, lb;
    splitf(h0 * att, hb, lb);
    oh[base + l] = hb; ol[base + l] = lb;
    splitf(h1 * att, hb, lb);
    oh[base + 64 + l] = hb; ol[base + 64 + l] = lb;
}

__global__ void bounds_kernel(const int* __restrict__ batch, int* __restrict__ gstart,
                              int* __restrict__ gend, int N) {
    int i = blockIdx.x * 256 + threadIdx.x;
    if (i >= N) return;
    int b = batch[i];
    if (i == 0 || batch[i - 1] != b) gstart[b] = i;
    if (i == N - 1 || batch[i + 1] != b) gend[b] = i + 1;
}

__global__ void pool2_kernel(const float* __restrict__ ha, const int* __restrict__ gstart,
                             const int* __restrict__ gend, float* __restrict__ pmax,
                             float* __restrict__ psum) {
    int g = blockIdx.x;
    int slice = blockIdx.y;
    int c = threadIdx.x;
    int s = gstart[g], e = gend[g];
    float vmax = 0.f, vsum = 0.f;
    for (int n = s + slice; n < e; n += PSPLIT) {
        float v = ha[(size_t)n * D + c];
        vmax = fmaxf(vmax, v);
        vsum += v;
    }
    atomicMax((int*)&pmax[g * D + c], __float_as_int(vmax));   // ha >= 0
    atomicAdd(&psum[g * D + c], vsum);
}

__global__ void mlp_kernel(const float* __restrict__ pmax, const float* __restrict__ psum,
                           const int* __restrict__ gstart, const int* __restrict__ gend,
                           const float* __restrict__ W1, const float* __restrict__ b1,
                           const float* __restrict__ W2, const float* __restrict__ b2,
                           float* __restrict__ out) {
    __shared__ float hid[128];
    __shared__ float pg[256];
    int g = blockIdx.x, tid = threadIdx.x;
    int cnt = max(gend[g] - gstart[g], 1);
    if (tid < 128) pg[tid] = pmax[g * D + tid];
    else pg[tid] = psum[g * D + (tid - 128)] / (float)cnt;
    __syncthreads();
    if (tid < 128) {
        float acc = b1[tid];
        for (int k = 0; k < 256; k++) acc += pg[k] * W1[k * 128 + tid];
        hid[tid] = fmaxf(acc, 0.f);
    }
    __syncthreads();
    if (tid < 16) {
        float acc = b2[tid];
        for (int k = 0; k < 128; k++) acc += hid[k] * W2[k * 16 + tid];
        out[g * 16 + tid] = acc;
    }
}

// ---------------- host ----------------
extern "C" void kernel_launch(void* const* d_in, const int* in_sizes, int n_in,
                              void* d_out, int out_size, void* d_ws, size_t ws_size,
                              hipStream_t stream) {
    const float* x       = (const float*)d_in[0];
    const int*   ei      = (const int*)d_in[1];
    const int*   batch   = (const int*)d_in[2];
    const float* ew      = (const float*)d_in[3];
    const float* Wa      = (const float*)d_in[4];
    const float* Wzm     = (const float*)d_in[5];
    const float* bzm     = (const float*)d_in[6];
    const float* Wzs     = (const float*)d_in[7];
    const float* bzs     = (const float*)d_in[8];
    const float* Wrm     = (const float*)d_in[9];
    const float* brm     = (const float*)d_in[10];
    const float* Wrs     = (const float*)d_in[11];
    const float* brs     = (const float*)d_in[12];
    const float* Whm     = (const float*)d_in[13];
    const float* bhm     = (const float*)d_in[14];
    const float* Whs     = (const float*)d_in[15];
    const float* bhs     = (const float*)d_in[16];
    const float* Whg     = (const float*)d_in[17];
    const float* bhg     = (const float*)d_in[18];
    const float* Whl     = (const float*)d_in[19];
    const float* bhl     = (const float*)d_in[20];
    const float* bias_z  = (const float*)d_in[21];
    const float* bias_r  = (const float*)d_in[22];
    const float* bias_h  = (const float*)d_in[23];
    const float* Wag     = (const float*)d_in[24];
    const float* bag     = (const float*)d_in[25];
    const float* Wae     = (const float*)d_in[26];
    const float* bae     = (const float*)d_in[27];
    const float* Wm1     = (const float*)d_in[28];
    const float* bm1     = (const float*)d_in[29];
    const float* Wm2     = (const float*)d_in[30];
    const float* bm2     = (const float*)d_in[31];
    float* out = (float*)d_out;

    const int N = in_sizes[0] / D;
    const int E = in_sizes[1] / 2;
    const size_t ND = (size_t)N * D;

    // workspace layout
    char* p = (char*)d_ws;
    unsigned short* h_hi = (unsigned short*)p;   p += ND * 4;           // hi + lo contiguous
    unsigned short* h_lo = h_hi + ND;
    float* tz = (float*)p;                       p += ND * 4;           // t, then z; att planes at head
    unsigned short* m_hi = (unsigned short*)p;   p += ND * 4;           // m (agg out)
    unsigned short* m_lo = m_hi + ND;
    unsigned short* rh_hi = (unsigned short*)p;  p += ND * 4;           // rh; emb-out f32 at head
    unsigned short* rh_lo = rh_hi + ND;
    int* cnt      = (int*)p;                     p += (size_t)N * 4;
    int* row_ptr  = (int*)p;                     p += (size_t)(N + 2) * 4 + 8;
    int* cursor   = (int*)p;                     p += (size_t)N * 4;
    int* partial  = (int*)p;                     p += 64 * 4;
    int* src_s    = (int*)p;                     p += (size_t)E * 4;
    float* ew_s   = (float*)p;                   p += (size_t)E * 4;
    float* bz     = (float*)p;                   p += D * 4;
    float* br     = (float*)p;                   p += D * 4;
    float* bci    = (float*)p;                   p += D * 4;
    int* gstart   = (int*)p;                     p += NGRAPHS * 4;
    int* gend     = (int*)p;                     p += NGRAPHS * 4;
    float* pmax   = (float*)p;                   p += NGRAPHS * D * 4;
    float* psum   = (float*)p;                   p += NGRAPHS * D * 4;
    unsigned short* wfrag = (unsigned short*)p;  p += 10 * 32768 * 2;
    unsigned short* ci_hi = (unsigned short*)p;  p += ND * 4;           // ci planes (new buffer)
    unsigned short* ci_lo = ci_hi + ND;

    // does ws have room for the dedicated ci buffer?
    const bool haveCi = ((size_t)(p - (char*)d_ws) <= ws_size);
    if (!haveCi) { ci_hi = m_hi; ci_lo = m_lo; }   // fallback: in-place, full-width launch

    const unsigned short* wfWa = wfrag + 0 * 32768;
    const unsigned short* wfZm = wfrag + 1 * 32768;
    const unsigned short* wfZs = wfrag + 2 * 32768;
    const unsigned short* wfRm = wfrag + 3 * 32768;
    const unsigned short* wfRs = wfrag + 4 * 32768;
    const unsigned short* wfHm = wfrag + 5 * 32768;
    const unsigned short* wfHs = wfrag + 6 * 32768;
    const unsigned short* wfHg = wfrag + 7 * 32768;
    const unsigned short* wfHl = wfrag + 8 * 32768;
    const unsigned short* wfAe = wfrag + 9 * 32768;

    // views for head stage
    unsigned short* at_hi = (unsigned short*)tz;        // att output planes reuse t/z space
    unsigned short* at_lo = at_hi + ND;
    float* embf = (float*)rh_hi;                        // emb output f32 reuses rh space

    const int rowTiles = (N + 63) / 64;
    dim3 gcs(rowTiles, 2);          // column-split grid (NJ=4)
    dim3 gfw(rowTiles, 1);          // full-width grid (NJ=8, fallback only)

    // h planes = split(x)
    split0_kernel<<<(int)((ND / 4 + 255) / 256), 256, 0, stream>>>(x, h_hi, h_lo, (int)(ND / 4));

    // weight frag prep
    wprep_kernel<<<10, 256, 0, stream>>>(Wa, Wzm, Wzs, Wrm, Wrs, Whm, Whs, Whg, Whl, Wae, wfrag);

    // CSR build
    hipMemsetAsync(cnt, 0, (size_t)N * 4, stream);
    count_kernel<<<(E + 255) / 256, 256, 0, stream>>>(ei, cnt, E);
    int nb = (N + 4095) / 4096;
    scan1_kernel<<<nb, 1024, 0, stream>>>(cnt, row_ptr, partial, N);
    scan2_kernel<<<1, 64, 0, stream>>>(partial, nb);
    scan3_kernel<<<(N + 255) / 256, 256, 0, stream>>>(row_ptr, partial, cursor, N, E);
    scatter_kernel<<<(E + 255) / 256, 256, 0, stream>>>(ei, ew, cursor, src_s, ew_s, E);

    biaspack_kernel<<<1, 128, 0, stream>>>(bzm, bzs, bias_z, brm, brs, bias_r,
                                           bhm, bhs, bias_h, bz, br, bci);

    for (int layer = 0; layer < 3; ++layer) {
        // t = h @ Wa  (f32)
        gmm<0, 4><<<gcs, 256, 0, stream>>>(h_hi, h_lo, nullptr, nullptr, wfWa, nullptr, nullptr, nullptr,
                                           tz, nullptr, nullptr, N, nullptr, nullptr, nullptr, nullptr, nullptr);
        // m = aggregate(t) -> planes
        agg_kernel<<<(N + 7) / 8, 256, 0, stream>>>(tz, m_hi, m_lo, row_ptr, src_s, ew_s, N);
        // z (f32 -> tz) and rh (planes) fused
        gmm<1, 4><<<gcs, 256, 0, stream>>>(m_hi, m_lo, h_hi, h_lo, wfZm, wfRm, wfZs, wfRs,
                                           tz, rh_hi, rh_lo, N, bz, br, nullptr, h_hi, h_lo);
        // ci = m@Whm + rh@Whs + bci -> ci planes
        if (haveCi) {
            gmm<2, 4><<<gcs, 256, 0, stream>>>(m_hi, m_lo, rh_hi, rh_lo, wfHm, nullptr, wfHs, nullptr,
                                               nullptr, ci_hi, ci_lo, N, bci, nullptr, nullptr, nullptr, nullptr);
        } else {
            // in-place over m: full-width blocks read their own rows entirely before writing
            gmm<2, 8><<<gfw, 256, 0, stream>>>(m_hi, m_lo, rh_hi, rh_lo, wfHm, nullptr, wfHs, nullptr,
                                               nullptr, ci_hi, ci_lo, N, bci, nullptr, nullptr, nullptr, nullptr);
        }
        // h = z*((ci@Whl + bhl)*sig(ci@Whg + bhg)) + (1-z)*h -> planes (elementwise-aligned, safe)
        gmm<3, 4><<<gcs, 256, 0, stream>>>(ci_hi, ci_lo, nullptr, nullptr, wfHg, wfHl, nullptr, nullptr,
                                           nullptr, h_hi, h_lo, N, bhg, bhl, tz, h_hi, h_lo);
    }

    // head
    att_kernel<<<(N + 3) / 4, 256, 0, stream>>>(h_hi, h_lo, Wag, bag, at_hi, at_lo, N);
    gmm<4, 4><<<gcs, 256, 0, stream>>>(at_hi, at_lo, nullptr, nullptr, wfAe, nullptr, nullptr, nullptr,
                                       embf, nullptr, nullptr, N, bae, nullptr, nullptr, nullptr, nullptr);

    hipMemsetAsync(gstart, 0, NGRAPHS * 4, stream);
    hipMemsetAsync(gend, 0, NGRAPHS * 4, stream);
    hipMemsetAsync(pmax, 0, NGRAPHS * D * 4, stream);
    hipMemsetAsync(psum, 0, NGRAPHS * D * 4, stream);
    bounds_kernel<<<(N + 255) / 256, 256, 0, stream>>>(batch, gstart, gend, N);
    dim3 pg(NGRAPHS, PSPLIT);
    pool2_kernel<<<pg, 128, 0, stream>>>(embf, gstart, gend, pmax, psum);
    mlp_kernel<<<NGRAPHS, 256, 0, stream>>>(pmax, psum, gstart, gend, Wm1, bm1, Wm2, bm2, out);
}

// Round 5
// 767.372 us; speedup vs baseline: 1.9329x; 1.0267x over previous
//
#include <hip/hip_runtime.h>
#include <hip/hip_bf16.h>

#define D 128
#define NGRAPHS 64
#define PSPLIT 16

typedef short short8 __attribute__((ext_vector_type(8)));
typedef float f32x4 __attribute__((ext_vector_type(4)));

__device__ __forceinline__ float sigf(float x) { return 1.0f / (1.0f + __expf(-x)); }

__device__ __forceinline__ unsigned short f2bf(float x) {
    unsigned u = __float_as_uint(x);
    return (unsigned short)((u + 0x7fffu + ((u >> 16) & 1u)) >> 16);
}
__device__ __forceinline__ float bf2f(unsigned short u) {
    return __uint_as_float(((unsigned)u) << 16);
}
__device__ __forceinline__ void splitf(float x, unsigned short& hb, unsigned short& lb) {
    hb = f2bf(x);
    lb = f2bf(x - bf2f(hb));
}

// ---------------- weight prep: f32 [128][128] -> frag-ordered bf16 hi/lo ----------------
// frag index f = ((j*4 + t)*64 + lane)*8 + s  maps to  W[t*32 + (lane>>4)*8 + s][j*16 + (lane&15)]
__global__ void wprep_kernel(const float* w0, const float* w1, const float* w2,
                             const float* w3, const float* w4, const float* w5,
                             const float* w6, const float* w7, const float* w8,
                             const float* w9, unsigned short* out) {
    const float* ws[10] = {w0, w1, w2, w3, w4, w5, w6, w7, w8, w9};
    const float* W = ws[blockIdx.x];
    unsigned short* oh = out + (size_t)blockIdx.x * 32768;
    unsigned short* ol = oh + 16384;
    for (int f = threadIdx.x; f < 16384; f += 256) {
        int s = f & 7;
        int lane = (f >> 3) & 63;
        int t = (f >> 9) & 3;
        int j = f >> 11;
        int k = t * 32 + ((lane >> 4) << 3) + s;
        int c = (j << 4) + (lane & 15);
        unsigned short hb, lb;
        splitf(W[k * 128 + c], hb, lb);
        oh[f] = hb;
        ol[f] = lb;
    }
}

// ---------------- fused MFMA GEMM over bf16 hi/lo planes, column-split ----------------
// Tile: 64 rows x (NJ*16) cols per block; grid = (ceil(N/64), 8/NJ). 4 waves, 16 rows each.
// Epilogue goes through a wave-local padded LDS tile so every global read/write in the
// epilogue is a 16B-per-lane vector op on contiguous row segments (was 32B segments).
// MODE 0: C = A0@W  (f32 out, no bias)                      [t = h@Wa]
// MODE 1: ZR fused: z = sig(m@Wzm + h@Wzs + b0) -> C f32;
//         rh = sig(m@Wrm + h@Wrs + b1) * h -> planes         [aux = h planes]
// MODE 2: CI: v = m@Whm + rh@Whs + b0 -> planes
// MODE 3: GH fused: g = sig(ci@Whg + b0); ht = (ci@Whl + b1)*g;
//         h = z*ht + (1-z)*h_old -> planes                   [auxf = z, aux = h planes]
// MODE 4: relu(A0@W + b0) -> C f32                           [att emb]
template <int MODE, int NJ>
__launch_bounds__(256)
__global__ void gmm(const unsigned short* __restrict__ A0h, const unsigned short* __restrict__ A0l,
                    const unsigned short* __restrict__ A1h, const unsigned short* __restrict__ A1l,
                    const unsigned short* __restrict__ WA0, const unsigned short* __restrict__ WB0,
                    const unsigned short* __restrict__ WA1, const unsigned short* __restrict__ WB1,
                    float* __restrict__ C, unsigned short* __restrict__ Ph, unsigned short* __restrict__ Pl,
                    int N, const float* __restrict__ bias0, const float* __restrict__ bias1,
                    const float* __restrict__ auxf,
                    const unsigned short* __restrict__ auxh, const unsigned short* __restrict__ auxl) {
    constexpr bool DUAL = (MODE == 1 || MODE == 3);
    constexpr int NP = (MODE == 1 || MODE == 2) ? 2 : 1;
    constexpr int COLS = NJ * 16;
    constexpr int STRIDE = COLS + 4;      // +4 pad: 2-way LDS bank aliasing only (free)
    constexpr int CPL = COLS / 4;         // cols per lane in epilogue

    __shared__ float sm[4 * 16 * STRIDE];

    const int tid = threadIdx.x;
    const int wave = tid >> 6;
    const int lane = tid & 63;
    const int by = blockIdx.y;
    const int r0 = blockIdx.x * 64 + wave * 16;

    f32x4 accA[NJ];
    f32x4 accB[NJ];
#pragma unroll
    for (int j = 0; j < NJ; ++j) {
        accA[j] = (f32x4){0.f, 0.f, 0.f, 0.f};
        accB[j] = (f32x4){0.f, 0.f, 0.f, 0.f};
    }

    int r = r0 + (lane & 15);
    const int arow = (r < N) ? r : (N - 1);   // clamped rows never stored
    const int kofs = (lane >> 4) << 3;

#pragma unroll
    for (int p = 0; p < NP; ++p) {
        const unsigned short* __restrict__ Ah = p ? A1h : A0h;
        const unsigned short* __restrict__ Al = p ? A1l : A0l;
        const unsigned short* __restrict__ Wa = p ? WA1 : WA0;
        const unsigned short* __restrict__ Wb = p ? WB1 : WB0;
#pragma unroll
        for (int t = 0; t < 4; ++t) {
            size_t ab = (size_t)arow * D + t * 32 + kofs;
            short8 ah = *(const short8*)(Ah + ab);
            short8 al = *(const short8*)(Al + ab);
#pragma unroll
            for (int jl = 0; jl < NJ; ++jl) {
                int jg = by * NJ + jl;
                const unsigned short* bp = Wa + ((((jg << 2) + t) << 6) + lane) * 8;
                short8 bh = *(const short8*)bp;
                short8 bl = *(const short8*)(bp + 16384);
                accA[jl] = __builtin_amdgcn_mfma_f32_16x16x32_bf16(ah, bh, accA[jl], 0, 0, 0);
                accA[jl] = __builtin_amdgcn_mfma_f32_16x16x32_bf16(al, bh, accA[jl], 0, 0, 0);
                accA[jl] = __builtin_amdgcn_mfma_f32_16x16x32_bf16(ah, bl, accA[jl], 0, 0, 0);
                if (DUAL) {
                    const unsigned short* bp2 = Wb + ((((jg << 2) + t) << 6) + lane) * 8;
                    short8 bh2 = *(const short8*)bp2;
                    short8 bl2 = *(const short8*)(bp2 + 16384);
                    accB[jl] = __builtin_amdgcn_mfma_f32_16x16x32_bf16(ah, bh2, accB[jl], 0, 0, 0);
                    accB[jl] = __builtin_amdgcn_mfma_f32_16x16x32_bf16(al, bh2, accB[jl], 0, 0, 0);
                    accB[jl] = __builtin_amdgcn_mfma_f32_16x16x32_bf16(ah, bl2, accB[jl], 0, 0, 0);
                }
            }
        }
    }

    // ---- epilogue via wave-local LDS transpose (no __syncthreads: wave-lockstep) ----
    float* mw = sm + wave * (16 * STRIDE);
    const int col0 = lane & 15;
    const int rb = (lane >> 4) << 2;
    const int lr = lane >> 2;             // local row 0..15
    const int cs = (lane & 3) * CPL;      // col segment start
    const int grow = r0 + lr;
    const int gcol = by * COLS + cs;
    const bool live = (grow < N);
    const size_t obase = (size_t)grow * D + gcol;

    float vA[CPL], vB[CPL];
    // phase A: stage accA, read back per-lane row segments
#pragma unroll
    for (int jl = 0; jl < NJ; ++jl)
#pragma unroll
        for (int reg = 0; reg < 4; ++reg)
            mw[(rb + reg) * STRIDE + jl * 16 + col0] = accA[jl][reg];
#pragma unroll
    for (int k = 0; k < CPL; k += 4)
        *(f32x4*)&vA[k] = *(const f32x4*)&mw[lr * STRIDE + cs + k];
    if (DUAL) {
        // phase B reuses the same LDS region (lockstep + lgkmcnt ordering keeps it safe)
#pragma unroll
        for (int jl = 0; jl < NJ; ++jl)
#pragma unroll
            for (int reg = 0; reg < 4; ++reg)
                mw[(rb + reg) * STRIDE + jl * 16 + col0] = accB[jl][reg];
#pragma unroll
        for (int k = 0; k < CPL; k += 4)
            *(f32x4*)&vB[k] = *(const f32x4*)&mw[lr * STRIDE + cs + k];
    }

    if (live) {
#pragma unroll
        for (int s8 = 0; s8 < CPL; s8 += 8) {
            size_t ob = obase + s8;
            int cb = gcol + s8;
            if (MODE == 0) {
                *(float4*)(C + ob) = *(float4*)&vA[s8];
                *(float4*)(C + ob + 4) = *(float4*)&vA[s8 + 4];
            } else if (MODE == 1) {
                float4 b0a = *(const float4*)(bias0 + cb);
                float4 b0b = *(const float4*)(bias0 + cb + 4);
                float4 b1a = *(const float4*)(bias1 + cb);
                float4 b1b = *(const float4*)(bias1 + cb + 4);
                float b0v[8] = {b0a.x, b0a.y, b0a.z, b0a.w, b0b.x, b0b.y, b0b.z, b0b.w};
                float b1v[8] = {b1a.x, b1a.y, b1a.z, b1a.w, b1b.x, b1b.y, b1b.z, b1b.w};
                short8 hh8 = *(const short8*)(auxh + ob);
                short8 ll8 = *(const short8*)(auxl + ob);
                float zv[8];
                short8 sh, sl;
#pragma unroll
                for (int k = 0; k < 8; ++k) {
                    zv[k] = sigf(vA[s8 + k] + b0v[k]);
                    float rr = sigf(vB[s8 + k] + b1v[k]);
                    float hv = bf2f((unsigned short)hh8[k]) + bf2f((unsigned short)ll8[k]);
                    unsigned short hb, lb;
                    splitf(rr * hv, hb, lb);
                    sh[k] = (short)hb; sl[k] = (short)lb;
                }
                *(float4*)(C + ob) = make_float4(zv[0], zv[1], zv[2], zv[3]);
                *(float4*)(C + ob + 4) = make_float4(zv[4], zv[5], zv[6], zv[7]);
                *(short8*)(Ph + ob) = sh;
                *(short8*)(Pl + ob) = sl;
            } else if (MODE == 2) {
                float4 b0a = *(const float4*)(bias0 + cb);
                float4 b0b = *(const float4*)(bias0 + cb + 4);
                float b0v[8] = {b0a.x, b0a.y, b0a.z, b0a.w, b0b.x, b0b.y, b0b.z, b0b.w};
                short8 sh, sl;
#pragma unroll
                for (int k = 0; k < 8; ++k) {
                    unsigned short hb, lb;
                    splitf(vA[s8 + k] + b0v[k], hb, lb);
                    sh[k] = (short)hb; sl[k] = (short)lb;
                }
                *(short8*)(Ph + ob) = sh;
                *(short8*)(Pl + ob) = sl;
            } else if (MODE == 3) {
                float4 b0a = *(const float4*)(bias0 + cb);
                float4 b0b = *(const float4*)(bias0 + cb + 4);
                float4 b1a = *(const float4*)(bias1 + cb);
                float4 b1b = *(const float4*)(bias1 + cb + 4);
                float b0v[8] = {b0a.x, b0a.y, b0a.z, b0a.w, b0b.x, b0b.y, b0b.z, b0b.w};
                float b1v[8] = {b1a.x, b1a.y, b1a.z, b1a.w, b1b.x, b1b.y, b1b.z, b1b.w};
                float4 za = *(const float4*)(auxf + ob);
                float4 zb = *(const float4*)(auxf + ob + 4);
                float zzv[8] = {za.x, za.y, za.z, za.w, zb.x, zb.y, zb.z, zb.w};
                short8 hh8 = *(const short8*)(auxh + ob);
                short8 ll8 = *(const short8*)(auxl + ob);
                short8 sh, sl;
#pragma unroll
                for (int k = 0; k < 8; ++k) {
                    float g = sigf(vA[s8 + k] + b0v[k]);
                    float ht = (vB[s8 + k] + b1v[k]) * g;
                    float hv = bf2f((unsigned short)hh8[k]) + bf2f((unsigned short)ll8[k]);
                    float v = zzv[k] * ht + (1.f - zzv[k]) * hv;
                    unsigned short hb, lb;
                    splitf(v, hb, lb);
                    sh[k] = (short)hb; sl[k] = (short)lb;
                }
                *(short8*)(Ph + ob) = sh;
                *(short8*)(Pl + ob) = sl;
            } else {  // MODE 4
                float4 b0a = *(const float4*)(bias0 + cb);
                float4 b0b = *(const float4*)(bias0 + cb + 4);
                float b0v[8] = {b0a.x, b0a.y, b0a.z, b0a.w, b0b.x, b0b.y, b0b.z, b0b.w};
                float rv[8];
#pragma unroll
                for (int k = 0; k < 8; ++k) rv[k] = fmaxf(vA[s8 + k] + b0v[k], 0.f);
                *(float4*)(C + ob) = make_float4(rv[0], rv[1], rv[2], rv[3]);
                *(float4*)(C + ob + 4) = make_float4(rv[4], rv[5], rv[6], rv[7]);
            }
        }
    }
}

// ---------------- initial split: x -> h planes ----------------
__global__ void split0_kernel(const float* __restrict__ x, unsigned short* __restrict__ hh,
                              unsigned short* __restrict__ hl, int ND4) {
    int i = blockIdx.x * 256 + threadIdx.x;
    if (i >= ND4) return;
    float4 v = ((const float4*)x)[i];
    float vv[4] = {v.x, v.y, v.z, v.w};
    unsigned short hb[4], lb[4];
#pragma unroll
    for (int k = 0; k < 4; ++k) splitf(vv[k], hb[k], lb[k]);
    unsigned long long uh = (unsigned long long)hb[0] | ((unsigned long long)hb[1] << 16) |
                            ((unsigned long long)hb[2] << 32) | ((unsigned long long)hb[3] << 48);
    unsigned long long ul = (unsigned long long)lb[0] | ((unsigned long long)lb[1] << 16) |
                            ((unsigned long long)lb[2] << 32) | ((unsigned long long)lb[3] << 48);
    ((unsigned long long*)hh)[i] = uh;
    ((unsigned long long*)hl)[i] = ul;
}

// ---------------- CSR build ----------------
__global__ void count_kernel(const int* __restrict__ ei, int* __restrict__ cnt, int E) {
    int e = blockIdx.x * 256 + threadIdx.x;
    if (e < E) atomicAdd(&cnt[ei[E + e]], 1);
}

__global__ void scan1_kernel(const int* __restrict__ cnt, int* __restrict__ exc,
                             int* __restrict__ partial, int N) {
    __shared__ int sd[1024];
    int tid = threadIdx.x;
    int base = blockIdx.x * 4096;
    int v[4], s = 0;
#pragma unroll
    for (int i = 0; i < 4; ++i) {
        int idx = base + tid * 4 + i;
        v[i] = (idx < N) ? cnt[idx] : 0;
        s += v[i];
    }
    sd[tid] = s;
    __syncthreads();
    for (int off = 1; off < 1024; off <<= 1) {
        int add = (tid >= off) ? sd[tid - off] : 0;
        __syncthreads();
        sd[tid] += add;
        __syncthreads();
    }
    int ex = sd[tid] - s;
#pragma unroll
    for (int i = 0; i < 4; ++i) {
        int idx = base + tid * 4 + i;
        if (idx < N) exc[idx] = ex;
        ex += v[i];
    }
    if (tid == 1023) partial[blockIdx.x] = sd[1023];
}

__global__ void scan2_kernel(int* __restrict__ partial, int nb) {
    __shared__ int sd[64];
    int tid = threadIdx.x;
    int v = (tid < nb) ? partial[tid] : 0;
    sd[tid] = v;
    __syncthreads();
    for (int off = 1; off < 64; off <<= 1) {
        int add = (tid >= off) ? sd[tid - off] : 0;
        __syncthreads();
        sd[tid] += add;
        __syncthreads();
    }
    if (tid < nb) partial[tid] = sd[tid] - v;
}

__global__ void scan3_kernel(int* __restrict__ row_ptr, const int* __restrict__ partial,
                             int* __restrict__ cursor, int N, int E) {
    int i = blockIdx.x * 256 + threadIdx.x;
    if (i < N) {
        int v = row_ptr[i] + partial[i >> 12];
        row_ptr[i] = v;
        cursor[i] = v;
    }
    if (i == 0) row_ptr[N] = E;
}

__global__ void scatter_kernel(const int* __restrict__ ei, const float* __restrict__ ew,
                               int* __restrict__ cursor, int* __restrict__ src_s,
                               float* __restrict__ ew_s, int E) {
    int e = blockIdx.x * 256 + threadIdx.x;
    if (e < E) {
        int d = ei[E + e];
        int pos = atomicAdd(&cursor[d], 1);
        src_s[pos] = ei[e];
        ew_s[pos] = ew[e];
    }
}

// ---------------- aggregation: m = t[n] + sum w_e * t[src_e], split-write ----------------
__global__ void agg_kernel(const float* __restrict__ t,
                           unsigned short* __restrict__ mh, unsigned short* __restrict__ ml,
                           const int* __restrict__ row_ptr, const int* __restrict__ src_s,
                           const float* __restrict__ ew_s, int N) {
    int n = blockIdx.x * 8 + (threadIdx.x >> 5);
    int c4 = threadIdx.x & 31;          // float4 index within row
    if (n >= N) return;
    const float4* tp = (const float4*)t;
    float4 a = tp[n * 32 + c4];
    float ax = a.x, ay = a.y, az = a.z, aw = a.w;
    int e0 = row_ptr[n], e1 = row_ptr[n + 1];
    int e = e0;
    for (; e + 4 <= e1; e += 4) {
        int s0 = src_s[e], s1 = src_s[e + 1], s2 = src_s[e + 2], s3 = src_s[e + 3];
        float w0 = ew_s[e], w1 = ew_s[e + 1], w2 = ew_s[e + 2], w3 = ew_s[e + 3];
        float4 v0 = tp[s0 * 32 + c4];
        float4 v1 = tp[s1 * 32 + c4];
        float4 v2 = tp[s2 * 32 + c4];
        float4 v3 = tp[s3 * 32 + c4];
        ax += w0 * v0.x + w1 * v1.x + w2 * v2.x + w3 * v3.x;
        ay += w0 * v0.y + w1 * v1.y + w2 * v2.y + w3 * v3.y;
        az += w0 * v0.z + w1 * v1.z + w2 * v2.z + w3 * v3.z;
        aw += w0 * v0.w + w1 * v1.w + w2 * v2.w + w3 * v3.w;
    }
    for (; e < e1; ++e) {
        int s = src_s[e];
        float w = ew_s[e];
        float4 v = tp[s * 32 + c4];
        ax += w * v.x; ay += w * v.y; az += w * v.z; aw += w * v.w;
    }
    float vv[4] = {ax, ay, az, aw};
    unsigned short hb[4], lb[4];
#pragma unroll
    for (int k = 0; k < 4; ++k) splitf(vv[k], hb[k], lb[k]);
    size_t i8 = (size_t)n * 32 + c4;
    unsigned long long uh = (unsigned long long)hb[0] | ((unsigned long long)hb[1] << 16) |
                            ((unsigned long long)hb[2] << 32) | ((unsigned long long)hb[3] << 48);
    unsigned long long ul = (unsigned long long)lb[0] | ((unsigned long long)lb[1] << 16) |
                            ((unsigned long long)lb[2] << 32) | ((unsigned long long)lb[3] << 48);
    ((unsigned long long*)mh)[i8] = uh;
    ((unsigned long long*)ml)[i8] = ul;
}

// ---------------- bias pack ----------------
__global__ void biaspack_kernel(const float* bzm, const float* bzs, const float* bz0,
                                const float* brm, const float* brs, const float* br0,
                                const float* bhm, const float* bhs, const float* bh0,
                                float* bz, float* br, float* bci) {
    int i = threadIdx.x;
    if (i < D) {
        bz[i] = bzm[i] + bzs[i] + bz0[i];
        br[i] = brm[i] + brs[i] + br0[i];
        bci[i] = bhm[i] + bhs[i] + bh0[i];
    }
}

// ---------------- head: hA = h * sigmoid(h@Wg + bg), split-write ----------------
__global__ void att_kernel(const unsigned short* __restrict__ hh, const unsigned short* __restrict__ hl,
                           const float* __restrict__ Wg, const float* __restrict__ bg,
                           unsigned short* __restrict__ oh, unsigned short* __restrict__ ol, int N) {
    int w = threadIdx.x >> 6, l = threadIdx.x & 63;
    int n = blockIdx.x * 4 + w;
    if (n >= N) return;
    size_t base = (size_t)n * D;
    float h0 = bf2f(hh[base + l]) + bf2f(hl[base + l]);
    float h1 = bf2f(hh[base + 64 + l]) + bf2f(hl[base + 64 + l]);
    float p = h0 * Wg[l] + h1 * Wg[64 + l];
#pragma unroll
    for (int off = 32; off; off >>= 1) p += __shfl_xor(p, off);
    float att = sigf(p + bg[0]);
    unsigned short hb, lb;
    splitf(h0 * att, hb, lb);
    oh[base + l] = hb; ol[base + l] = lb;
    splitf(h1 * att, hb, lb);
    oh[base + 64 + l] = hb; ol[base + 64 + l] = lb;
}

__global__ void bounds_kernel(const int* __restrict__ batch, int* __restrict__ gstart,
                              int* __restrict__ gend, int N) {
    int i = blockIdx.x * 256 + threadIdx.x;
    if (i >= N) return;
    int b = batch[i];
    if (i == 0 || batch[i - 1] != b) gstart[b] = i;
    if (i == N - 1 || batch[i + 1] != b) gend[b] = i + 1;
}

__global__ void pool2_kernel(const float* __restrict__ ha, const int* __restrict__ gstart,
                             const int* __restrict__ gend, float* __restrict__ pmax,
                             float* __restrict__ psum) {
    int g = blockIdx.x;
    int slice = blockIdx.y;
    int c = threadIdx.x;
    int s = gstart[g], e = gend[g];
    float vmax = 0.f, vsum = 0.f;
    for (int n = s + slice; n < e; n += PSPLIT) {
        float v = ha[(size_t)n * D + c];
        vmax = fmaxf(vmax, v);
        vsum += v;
    }
    atomicMax((int*)&pmax[g * D + c], __float_as_int(vmax));   // ha >= 0
    atomicAdd(&psum[g * D + c], vsum);
}

__global__ void mlp_kernel(const float* __restrict__ pmax, const float* __restrict__ psum,
                           const int* __restrict__ gstart, const int* __restrict__ gend,
                           const float* __restrict__ W1, const float* __restrict__ b1,
                           const float* __restrict__ W2, const float* __restrict__ b2,
                           float* __restrict__ out) {
    __shared__ float hid[128];
    __shared__ float pg[256];
    int g = blockIdx.x, tid = threadIdx.x;
    int cnt = max(gend[g] - gstart[g], 1);
    if (tid < 128) pg[tid] = pmax[g * D + tid];
    else pg[tid] = psum[g * D + (tid - 128)] / (float)cnt;
    __syncthreads();
    if (tid < 128) {
        float acc = b1[tid];
        for (int k = 0; k < 256; k++) acc += pg[k] * W1[k * 128 + tid];
        hid[tid] = fmaxf(acc, 0.f);
    }
    __syncthreads();
    if (tid < 16) {
        float acc = b2[tid];
        for (int k = 0; k < 128; k++) acc += hid[k] * W2[k * 16 + tid];
        out[g * 16 + tid] = acc;
    }
}

// ---------------- host ----------------
extern "C" void kernel_launch(void* const* d_in, const int* in_sizes, int n_in,
                              void* d_out, int out_size, void* d_ws, size_t ws_size,
                              hipStream_t stream) {
    const float* x       = (const float*)d_in[0];
    const int*   ei      = (const int*)d_in[1];
    const int*   batch   = (const int*)d_in[2];
    const float* ew      = (const float*)d_in[3];
    const float* Wa      = (const float*)d_in[4];
    const float* Wzm     = (const float*)d_in[5];
    const float* bzm     = (const float*)d_in[6];
    const float* Wzs     = (const float*)d_in[7];
    const float* bzs     = (const float*)d_in[8];
    const float* Wrm     = (const float*)d_in[9];
    const float* brm     = (const float*)d_in[10];
    const float* Wrs     = (const float*)d_in[11];
    const float* brs     = (const float*)d_in[12];
    const float* Whm     = (const float*)d_in[13];
    const float* bhm     = (const float*)d_in[14];
    const float* Whs     = (const float*)d_in[15];
    const float* bhs     = (const float*)d_in[16];
    const float* Whg     = (const float*)d_in[17];
    const float* bhg     = (const float*)d_in[18];
    const float* Whl     = (const float*)d_in[19];
    const float* bhl     = (const float*)d_in[20];
    const float* bias_z  = (const float*)d_in[21];
    const float* bias_r  = (const float*)d_in[22];
    const float* bias_h  = (const float*)d_in[23];
    const float* Wag     = (const float*)d_in[24];
    const float* bag     = (const float*)d_in[25];
    const float* Wae     = (const float*)d_in[26];
    const float* bae     = (const float*)d_in[27];
    const float* Wm1     = (const float*)d_in[28];
    const float* bm1     = (const float*)d_in[29];
    const float* Wm2     = (const float*)d_in[30];
    const float* bm2     = (const float*)d_in[31];
    float* out = (float*)d_out;

    const int N = in_sizes[0] / D;
    const int E = in_sizes[1] / 2;
    const size_t ND = (size_t)N * D;

    // workspace layout
    char* p = (char*)d_ws;
    unsigned short* h_hi = (unsigned short*)p;   p += ND * 4;           // hi + lo contiguous
    unsigned short* h_lo = h_hi + ND;
    float* tz = (float*)p;                       p += ND * 4;           // t, then z; att planes at head
    unsigned short* m_hi = (unsigned short*)p;   p += ND * 4;           // m (agg out)
    unsigned short* m_lo = m_hi + ND;
    unsigned short* rh_hi = (unsigned short*)p;  p += ND * 4;           // rh; emb-out f32 at head
    unsigned short* rh_lo = rh_hi + ND;
    int* cnt      = (int*)p;                     p += (size_t)N * 4;
    int* row_ptr  = (int*)p;                     p += (size_t)(N + 2) * 4 + 8;
    int* cursor   = (int*)p;                     p += (size_t)N * 4;
    int* partial  = (int*)p;                     p += 64 * 4;
    int* src_s    = (int*)p;                     p += (size_t)E * 4;
    float* ew_s   = (float*)p;                   p += (size_t)E * 4;
    float* bz     = (float*)p;                   p += D * 4;
    float* br     = (float*)p;                   p += D * 4;
    float* bci    = (float*)p;                   p += D * 4;
    int* gstart   = (int*)p;                     p += NGRAPHS * 4;
    int* gend     = (int*)p;                     p += NGRAPHS * 4;
    float* pmax   = (float*)p;                   p += NGRAPHS * D * 4;
    float* psum   = (float*)p;                   p += NGRAPHS * D * 4;
    unsigned short* wfrag = (unsigned short*)p;  p += 10 * 32768 * 2;
    unsigned short* ci_hi = (unsigned short*)p;  p += ND * 4;           // ci planes (dedicated)
    unsigned short* ci_lo = ci_hi + ND;

    const bool haveCi = ((size_t)(p - (char*)d_ws) <= ws_size);
    if (!haveCi) { ci_hi = m_hi; ci_lo = m_lo; }   // fallback: in-place, full-width launch

    const unsigned short* wfWa = wfrag + 0 * 32768;
    const unsigned short* wfZm = wfrag + 1 * 32768;
    const unsigned short* wfZs = wfrag + 2 * 32768;
    const unsigned short* wfRm = wfrag + 3 * 32768;
    const unsigned short* wfRs = wfrag + 4 * 32768;
    const unsigned short* wfHm = wfrag + 5 * 32768;
    const unsigned short* wfHs = wfrag + 6 * 32768;
    const unsigned short* wfHg = wfrag + 7 * 32768;
    const unsigned short* wfHl = wfrag + 8 * 32768;
    const unsigned short* wfAe = wfrag + 9 * 32768;

    // views for head stage
    unsigned short* at_hi = (unsigned short*)tz;        // att output planes reuse t/z space
    unsigned short* at_lo = at_hi + ND;
    float* embf = (float*)rh_hi;                        // emb output f32 reuses rh space

    const int rowTiles = (N + 63) / 64;
    dim3 gcs(rowTiles, 2);          // column-split grid (NJ=4)
    dim3 gfw(rowTiles, 1);          // full-width grid (NJ=8, fallback only)

    // h planes = split(x)
    split0_kernel<<<(int)((ND / 4 + 255) / 256), 256, 0, stream>>>(x, h_hi, h_lo, (int)(ND / 4));

    // weight frag prep
    wprep_kernel<<<10, 256, 0, stream>>>(Wa, Wzm, Wzs, Wrm, Wrs, Whm, Whs, Whg, Whl, Wae, wfrag);

    // CSR build
    hipMemsetAsync(cnt, 0, (size_t)N * 4, stream);
    count_kernel<<<(E + 255) / 256, 256, 0, stream>>>(ei, cnt, E);
    int nb = (N + 4095) / 4096;
    scan1_kernel<<<nb, 1024, 0, stream>>>(cnt, row_ptr, partial, N);
    scan2_kernel<<<1, 64, 0, stream>>>(partial, nb);
    scan3_kernel<<<(N + 255) / 256, 256, 0, stream>>>(row_ptr, partial, cursor, N, E);
    scatter_kernel<<<(E + 255) / 256, 256, 0, stream>>>(ei, ew, cursor, src_s, ew_s, E);

    biaspack_kernel<<<1, 128, 0, stream>>>(bzm, bzs, bias_z, brm, brs, bias_r,
                                           bhm, bhs, bias_h, bz, br, bci);

    for (int layer = 0; layer < 3; ++layer) {
        // t = h @ Wa  (f32)
        gmm<0, 4><<<gcs, 256, 0, stream>>>(h_hi, h_lo, nullptr, nullptr, wfWa, nullptr, nullptr, nullptr,
                                           tz, nullptr, nullptr, N, nullptr, nullptr, nullptr, nullptr, nullptr);
        // m = aggregate(t) -> planes
        agg_kernel<<<(N + 7) / 8, 256, 0, stream>>>(tz, m_hi, m_lo, row_ptr, src_s, ew_s, N);
        // z (f32 -> tz) and rh (planes) fused
        gmm<1, 4><<<gcs, 256, 0, stream>>>(m_hi, m_lo, h_hi, h_lo, wfZm, wfRm, wfZs, wfRs,
                                           tz, rh_hi, rh_lo, N, bz, br, nullptr, h_hi, h_lo);
        // ci = m@Whm + rh@Whs + bci -> ci planes
        if (haveCi) {
            gmm<2, 4><<<gcs, 256, 0, stream>>>(m_hi, m_lo, rh_hi, rh_lo, wfHm, nullptr, wfHs, nullptr,
                                               nullptr, ci_hi, ci_lo, N, bci, nullptr, nullptr, nullptr, nullptr);
        } else {
            gmm<2, 8><<<gfw, 256, 0, stream>>>(m_hi, m_lo, rh_hi, rh_lo, wfHm, nullptr, wfHs, nullptr,
                                               nullptr, ci_hi, ci_lo, N, bci, nullptr, nullptr, nullptr, nullptr);
        }
        // h = z*((ci@Whl + bhl)*sig(ci@Whg + bhg)) + (1-z)*h -> planes (elementwise-aligned, safe)
        gmm<3, 4><<<gcs, 256, 0, stream>>>(ci_hi, ci_lo, nullptr, nullptr, wfHg, wfHl, nullptr, nullptr,
                                           nullptr, h_hi, h_lo, N, bhg, bhl, tz, h_hi, h_lo);
    }

    // head
    att_kernel<<<(N + 3) / 4, 256, 0, stream>>>(h_hi, h_lo, Wag, bag, at_hi, at_lo, N);
    gmm<4, 4><<<gcs, 256, 0, stream>>>(at_hi, at_lo, nullptr, nullptr, wfAe, nullptr, nullptr, nullptr,
                                       embf, nullptr, nullptr, N, bae, nullptr, nullptr, nullptr, nullptr);

    hipMemsetAsync(gstart, 0, NGRAPHS * 4, stream);
    hipMemsetAsync(gend, 0, NGRAPHS * 4, stream);
    hipMemsetAsync(pmax, 0, NGRAPHS * D * 4, stream);
    hipMemsetAsync(psum, 0, NGRAPHS * D * 4, stream);
    bounds_kernel<<<(N + 255) / 256, 256, 0, stream>>>(batch, gstart, gend, N);
    dim3 pg(NGRAPHS, PSPLIT);
    pool2_kernel<<<pg, 128, 0, stream>>>(embf, gstart, gend, pmax, psum);
    mlp_kernel<<<NGRAPHS, 256, 0, stream>>>(pmax, psum, gstart, gend, Wm1, bm1, Wm2, bm2, out);
}